// Round 5
// baseline (559.153 us; speedup 1.0000x reference)
//
#include <hip/hip_runtime.h>
#include <math.h>

#define F1 64   // input/hidden features
#define F2 40   // classes

#define SCAN_B 256
#define SCAN_CHUNK 4
#define SCAN_TILE (SCAN_B * SCAN_CHUNK)   // 1024 elems per block

// ---------- utility ----------
__global__ void k_zero_int(int* p, int n) {
    int i = blockIdx.x * blockDim.x + threadIdx.x;
    if (i < n) p[i] = 0;
}

__global__ void k_count_int(const int* __restrict__ dst, int* deg, int e) {
    int i = blockIdx.x * blockDim.x + threadIdx.x;
    if (i < e) atomicAdd(&deg[dst[i]], 1);
}

__global__ void k_dinv(const int* __restrict__ deg, float* __restrict__ dinv, int n) {
    int i = blockIdx.x * blockDim.x + threadIdx.x;
    if (i < n) dinv[i] = rsqrtf((float)(deg[i] + 1));   // +1 = self loop
}

// ---------- multi-block exclusive scan, 3 phases ----------
__global__ __launch_bounds__(SCAN_B) void k_blocksum(const int* __restrict__ deg,
                                                     int* __restrict__ partial, int n) {
    int base = blockIdx.x * SCAN_TILE + threadIdx.x * SCAN_CHUNK;
    int s = 0;
#pragma unroll
    for (int j = 0; j < SCAN_CHUNK; ++j) { int i = base + j; if (i < n) s += deg[i]; }
    for (int o = 32; o; o >>= 1) s += __shfl_down(s, o);
    __shared__ int sh[4];
    if ((threadIdx.x & 63) == 0) sh[threadIdx.x >> 6] = s;
    __syncthreads();
    if (threadIdx.x == 0) partial[blockIdx.x] = sh[0] + sh[1] + sh[2] + sh[3];
}

__global__ __launch_bounds__(256) void k_scan_partial(int* partial, int g) {
    __shared__ int sh[256];
    int t = threadIdx.x;
    int v = (t < g) ? partial[t] : 0;
    sh[t] = v;
    __syncthreads();
    for (int off = 1; off < 256; off <<= 1) {
        int u = (t >= off) ? sh[t - off] : 0;
        __syncthreads();
        sh[t] += u;
        __syncthreads();
    }
    if (t < g) partial[t] = (t == 0) ? 0 : sh[t - 1];
}

__global__ __launch_bounds__(SCAN_B) void k_scan_out(const int* __restrict__ deg,
                                                     const int* __restrict__ partial,
                                                     int* __restrict__ row_ptr,
                                                     int* __restrict__ cnt, int n) {
    int t = threadIdx.x;
    int base = blockIdx.x * SCAN_TILE + t * SCAN_CHUNK;
    int v[SCAN_CHUNK];
    int s = 0;
#pragma unroll
    for (int j = 0; j < SCAN_CHUNK; ++j) { int i = base + j; v[j] = (i < n) ? deg[i] : 0; s += v[j]; }
    int lane = t & 63;
    int sc = s;
    for (int o = 1; o < 64; o <<= 1) { int u = __shfl_up(sc, o); if (lane >= o) sc += u; }
    __shared__ int wsum[4];
    if (lane == 63) wsum[t >> 6] = sc;
    __syncthreads();
    int w = t >> 6, woff = 0;
#pragma unroll
    for (int k = 0; k < 4; ++k) if (k < w) woff += wsum[k];
    int excl = partial[blockIdx.x] + woff + (sc - s);
#pragma unroll
    for (int j = 0; j < SCAN_CHUNK; ++j) {
        int i = base + j;
        if (i < n) { row_ptr[i] = excl; cnt[i] = excl; excl += v[j]; }
    }
    if (base <= n - 1 && n - 1 < base + SCAN_CHUNK) row_ptr[n] = excl;  // total = E
}

// ---------- bucket edges by dst: single random atomic per edge ----------
__global__ void k_permute(const int* __restrict__ src, const int* __restrict__ dst,
                          int* cnt, int* __restrict__ srcs, int e) {
    int i = blockIdx.x * blockDim.x + threadIdx.x;
    if (i < e) {
        int pos = atomicAdd(&cnt[dst[i]], 1);   // cnt pre-seeded with row_ptr
        srcs[pos] = src[i];
    }
}

// ---------- GEMM1: h = x @ W1   (N x 64) @ (64 x 64) ----------
__global__ __launch_bounds__(256) void k_gemm1(const float* __restrict__ x,
                                               const float* __restrict__ W,
                                               float* __restrict__ h, int n) {
    __shared__ float Ws[64 * 64];
    __shared__ float xs[4][64];
    int tid = threadIdx.x;
#pragma unroll
    for (int i = 0; i < 16; ++i) Ws[tid + i * 256] = W[tid + i * 256];
    int r = tid >> 6, c = tid & 63;
    int row = blockIdx.x * 4 + r;
    xs[r][c] = (row < n) ? x[row * 64 + c] : 0.0f;
    __syncthreads();
    float acc = 0.0f;
#pragma unroll
    for (int k = 0; k < 64; k += 4) {
        float4 xv = *(const float4*)&xs[r][k];
        acc = fmaf(xv.x, Ws[(k + 0) * 64 + c], acc);
        acc = fmaf(xv.y, Ws[(k + 1) * 64 + c], acc);
        acc = fmaf(xv.z, Ws[(k + 2) * 64 + c], acc);
        acc = fmaf(xv.w, Ws[(k + 3) * 64 + c], acc);
    }
    if (row < n) h[row * 64 + c] = acc;
}

// ---------- CSR gather-aggregate layer 1: one wave per node, lane = feature ----------
__global__ __launch_bounds__(256) void k_gather(const float* __restrict__ h,
                                                const int* __restrict__ srcs,
                                                const int* __restrict__ row_ptr,
                                                const float* __restrict__ dinv,
                                                const float* __restrict__ b,
                                                float* __restrict__ out, int n) {
    int node = (int)(((long long)blockIdx.x * 256 + threadIdx.x) >> 6);
    int lane = threadIdx.x & 63;
    if (node >= n) return;
    float di = dinv[node];
    float acc = b[lane] + h[(long long)node * 64 + lane] * di * di;
    int e = row_ptr[node], end = row_ptr[node + 1];
    for (; e + 3 < end; e += 4) {
        int s0 = srcs[e], s1 = srcs[e + 1], s2 = srcs[e + 2], s3 = srcs[e + 3];
        float v0 = h[(long long)s0 * 64 + lane];
        float v1 = h[(long long)s1 * 64 + lane];
        float v2 = h[(long long)s2 * 64 + lane];
        float v3 = h[(long long)s3 * 64 + lane];
        float n0 = dinv[s0] * di, n1 = dinv[s1] * di, n2 = dinv[s2] * di, n3 = dinv[s3] * di;
        acc = fmaf(v0, n0, acc);
        acc = fmaf(v1, n1, acc);
        acc = fmaf(v2, n2, acc);
        acc = fmaf(v3, n3, acc);
    }
    for (; e < end; ++e) {
        int s0 = srcs[e];
        acc = fmaf(h[(long long)s0 * 64 + lane], dinv[s0] * di, acc);
    }
    out[(long long)node * 64 + lane] = acc;
}

// ---------- layer-2 transform: t = relu(agg1) @ W2  (N x 40) ----------
// lane = class; W2 column in 64 VGPRs; agg row via wave-uniform s_loads.
__global__ __launch_bounds__(256) void k_trans2(const float* __restrict__ agg,
                                                const float* __restrict__ W2,
                                                float* __restrict__ t, int n,
                                                int nwaves) {
    int wid = blockIdx.x * 4 + (threadIdx.x >> 6);
    int lane = threadIdx.x & 63;
    float wcol[64];
#pragma unroll
    for (int k = 0; k < 64; ++k)
        wcol[k] = (lane < 40) ? W2[k * 40 + lane] : 0.0f;
    for (int node = wid; node < n; node += nwaves) {
        int node_u = __builtin_amdgcn_readfirstlane(node);
        const float* arow = agg + (size_t)node_u * 64;
        float acc = 0.0f;
#pragma unroll
        for (int k4 = 0; k4 < 16; ++k4) {
            float4 a = *(const float4*)(arow + k4 * 4);   // wave-uniform -> s_load
            acc = fmaf(fmaxf(a.x, 0.0f), wcol[k4 * 4 + 0], acc);
            acc = fmaf(fmaxf(a.y, 0.0f), wcol[k4 * 4 + 1], acc);
            acc = fmaf(fmaxf(a.z, 0.0f), wcol[k4 * 4 + 2], acc);
            acc = fmaf(fmaxf(a.w, 0.0f), wcol[k4 * 4 + 3], acc);
        }
        if (lane < 40) t[(size_t)node_u * 40 + lane] = acc;
    }
}

// ---------- layer-2 gather (40-wide) + bias + log_softmax ----------
__global__ __launch_bounds__(256) void k_gather40(const float* __restrict__ t,
                                                  const int* __restrict__ srcs,
                                                  const int* __restrict__ row_ptr,
                                                  const float* __restrict__ dinv,
                                                  const float* __restrict__ b2,
                                                  float* __restrict__ out, int n) {
    int node = (int)(((long long)blockIdx.x * 256 + threadIdx.x) >> 6);
    int lane = threadIdx.x & 63;
    if (node >= n) return;
    bool act = lane < 40;
    float di = dinv[node];
    float acc = act ? (b2[lane] + t[(long long)node * 40 + lane] * di * di) : 0.0f;
    int e = row_ptr[node], end = row_ptr[node + 1];
    for (; e + 3 < end; e += 4) {
        int s0 = srcs[e], s1 = srcs[e + 1], s2 = srcs[e + 2], s3 = srcs[e + 3];
        float v0 = act ? t[(long long)s0 * 40 + lane] : 0.0f;
        float v1 = act ? t[(long long)s1 * 40 + lane] : 0.0f;
        float v2 = act ? t[(long long)s2 * 40 + lane] : 0.0f;
        float v3 = act ? t[(long long)s3 * 40 + lane] : 0.0f;
        float n0 = dinv[s0] * di, n1 = dinv[s1] * di, n2 = dinv[s2] * di, n3 = dinv[s3] * di;
        acc = fmaf(v0, n0, acc);
        acc = fmaf(v1, n1, acc);
        acc = fmaf(v2, n2, acc);
        acc = fmaf(v3, n3, acc);
    }
    for (; e < end; ++e) {
        int s0 = srcs[e];
        float v0 = act ? t[(long long)s0 * 40 + lane] : 0.0f;
        acc = fmaf(v0, dinv[s0] * di, acc);
    }
    // log_softmax across the 40 classes held lane-wise
    float v = act ? acc : -INFINITY;
    float m = v;
    for (int o = 32; o; o >>= 1) m = fmaxf(m, __shfl_xor(m, o));
    float ex = act ? expf(v - m) : 0.0f;
    float s = ex;
    for (int o = 32; o; o >>= 1) s += __shfl_xor(s, o);
    float r = v - m - logf(s);
    if (act) out[(long long)node * 40 + lane] = r;
}

extern "C" void kernel_launch(void* const* d_in, const int* in_sizes, int n_in,
                              void* d_out, int out_size, void* d_ws, size_t ws_size,
                              hipStream_t stream) {
    const float* x  = (const float*)d_in[0];
    const int*   ei = (const int*)d_in[1];
    const float* W1 = (const float*)d_in[2];
    const float* b1 = (const float*)d_in[3];
    const float* W2 = (const float*)d_in[4];
    const float* b2 = (const float*)d_in[5];

    const int N = in_sizes[0] / F1;      // 100000
    const int E = in_sizes[1] / 2;       // 1600000
    const int* src = ei;
    const int* dst = ei + E;

    // workspace layout
    int*   ideg    = (int*)d_ws;                       // N
    int*   row_ptr = ideg + N;                         // N+1
    int*   cnt     = row_ptr + N + 1;                  // N
    float* dinv    = (float*)(cnt + N);                // N
    int*   partial = (int*)(dinv + N);                 // 256
    int*   srcs    = partial + 256;                    // E
    float* bufA    = (float*)(srcs + E);               // N*64  (h1, later t=N*40)
    float* bufB    = bufA + (size_t)N * F1;            // N*64  (agg1)
    float* outp    = (float*)d_out;                    // N*40

    const int B = 256;
    const int G = (N + SCAN_TILE - 1) / SCAN_TILE;     // scan blocks (98)

    // --- CSR build ---
    k_zero_int<<<(N + B - 1) / B, B, 0, stream>>>(ideg, N);
    k_count_int<<<(E + B - 1) / B, B, 0, stream>>>(dst, ideg, E);
    k_dinv<<<(N + B - 1) / B, B, 0, stream>>>(ideg, dinv, N);
    k_blocksum<<<G, SCAN_B, 0, stream>>>(ideg, partial, N);
    k_scan_partial<<<1, 256, 0, stream>>>(partial, G);
    k_scan_out<<<G, SCAN_B, 0, stream>>>(ideg, partial, row_ptr, cnt, N);
    k_permute<<<(E + B - 1) / B, B, 0, stream>>>(src, dst, cnt, srcs, E);

    // --- layer 1: GEMM then gather-aggregate (+b1) ---
    k_gemm1<<<(N + 3) / 4, B, 0, stream>>>(x, W1, bufA, N);
    k_gather<<<(N + 3) / 4, B, 0, stream>>>(bufA, srcs, row_ptr, dinv, b1, bufB, N);

    // --- layer 2: transform first (reference order), then 40-wide gather + softmax ---
    const int TB = 2048;
    k_trans2<<<TB, B, 0, stream>>>(bufB, W2, bufA, N, TB * 4);
    k_gather40<<<(N + 3) / 4, B, 0, stream>>>(bufA, srcs, row_ptr, dinv, b2, outp, N);
}

// Round 6
// 397.768 us; speedup vs baseline: 1.4057x; 1.4057x over previous
//
#include <hip/hip_runtime.h>
#include <math.h>

#define F1 64   // input/hidden features
#define F2 40   // classes
#define NB 512      // buckets for CSR build
#define TILE 4096   // edges per k_bscatter/k_bhist block (256 thr x 16)
#define CAP 12288   // max LDS-staged edges per bucket in k_bfinal (48 KB)

// ---------- utility ----------
__global__ void k_zero_int(int* p, int n) {
    int i = blockIdx.x * blockDim.x + threadIdx.x;
    if (i < n) p[i] = 0;
}

// ---------- pass 1a: bucket histogram (coalesced reads, LDS hist) ----------
__global__ __launch_bounds__(256) void k_bhist(const int* __restrict__ dst,
                                               int* __restrict__ bcnt, int e, int bsh) {
    __shared__ int h[NB];
    int tid = threadIdx.x;
    for (int i = tid; i < NB; i += 256) h[i] = 0;
    __syncthreads();
    int base = blockIdx.x * TILE;
    int lim = min(base + TILE, e);
    for (int i = base + tid; i < lim; i += 256) atomicAdd(&h[dst[i] >> bsh], 1);
    __syncthreads();
    for (int i = tid; i < NB; i += 256) if (h[i]) atomicAdd(&bcnt[i], h[i]);
}

// ---------- pass 1b: scan of bucket counts (single block) ----------
__global__ __launch_bounds__(NB) void k_bscan(const int* __restrict__ bcnt,
                                              int* __restrict__ bptr, int* __restrict__ gcur,
                                              int* __restrict__ row_ptr, int n, int e) {
    __shared__ int sh[NB];
    int t = threadIdx.x;
    sh[t] = bcnt[t];
    __syncthreads();
    for (int off = 1; off < NB; off <<= 1) {
        int v = (t >= off) ? sh[t - off] : 0;
        __syncthreads();
        sh[t] += v;
        __syncthreads();
    }
    int ex = t ? sh[t - 1] : 0;
    bptr[t] = ex;
    gcur[t] = ex;
    if (t == NB - 1) bptr[NB] = sh[NB - 1];
    if (t == 0) row_ptr[n] = e;   // global total
}

// ---------- pass 1c: bucket the (src,dst) pairs, LDS-reordered coalesced writes ----------
__global__ __launch_bounds__(256) void k_bscatter(const int* __restrict__ src,
                                                  const int* __restrict__ dst,
                                                  int* gcur,
                                                  unsigned long long* __restrict__ pairs,
                                                  int e, int bsh) {
    __shared__ int lhist[NB];
    __shared__ int lstart[NB];
    __shared__ int delta[NB];
    __shared__ unsigned long long stage[TILE];
    int tid = threadIdx.x;
    for (int i = tid; i < NB; i += 256) lhist[i] = 0;
    __syncthreads();
    int base = blockIdx.x * TILE;
    int cnt = min(TILE, e - base);
    int sA[16], dA[16], rA[16];
#pragma unroll
    for (int k = 0; k < 16; ++k) {
        int i = base + k * 256 + tid;
        if (i < e) {
            sA[k] = src[i];
            dA[k] = dst[i];
            rA[k] = atomicAdd(&lhist[dA[k] >> bsh], 1);
        }
    }
    __syncthreads();
    // exclusive scan lhist -> lstart (wave 0, 8 contiguous entries per lane)
    if (tid < 64) {
        int v[8];
        int b0 = tid * 8, s = 0;
#pragma unroll
        for (int j = 0; j < 8; ++j) { v[j] = lhist[b0 + j]; s += v[j]; }
        int sc = s;
        for (int o = 1; o < 64; o <<= 1) { int u = __shfl_up(sc, o); if (tid >= o) sc += u; }
        int ex = sc - s;
#pragma unroll
        for (int j = 0; j < 8; ++j) { lstart[b0 + j] = ex; ex += v[j]; }
    }
    __syncthreads();
    // reserve global space per bucket
    for (int i = tid; i < NB; i += 256) {
        int c = lhist[i];
        if (c) delta[i] = atomicAdd(&gcur[i], c) - lstart[i];
    }
    __syncthreads();
    // reorder into LDS by bucket
#pragma unroll
    for (int k = 0; k < 16; ++k) {
        int i = base + k * 256 + tid;
        if (i < e) {
            int b = dA[k] >> bsh;
            stage[lstart[b] + rA[k]] =
                ((unsigned long long)(unsigned)sA[k] << 32) | (unsigned)dA[k];
        }
    }
    __syncthreads();
    // coalesced-ish write out (runs contiguous per bucket)
    for (int p = tid; p < cnt; p += 256) {
        unsigned long long pr = stage[p];
        int b = ((int)(unsigned)pr) >> bsh;
        pairs[delta[b] + p] = pr;
    }
}

// ---------- pass 2: per-bucket CSR finalize (row_ptr, dinv, srcs) — no global atomics ----------
__global__ __launch_bounds__(256) void k_bfinal(const unsigned long long* __restrict__ pairs,
                                                const int* __restrict__ bptr,
                                                int* __restrict__ srcs,
                                                int* __restrict__ row_ptr,
                                                float* __restrict__ dinv,
                                                int n, int bsh) {
    __shared__ int ldeg[NB];
    __shared__ int lrow[NB];
    __shared__ int lcur[NB];
    __shared__ int sstage[CAP];
    int b = blockIdx.x, tid = threadIdx.x;
    int beg = bptr[b], end = bptr[b + 1];
    int cnt = end - beg;
    int node0 = b << bsh;
    int bnodes = 1 << bsh;   // 256 (or 512 for larger N)
    for (int i = tid; i < bnodes; i += 256) { ldeg[i] = 0; lcur[i] = 0; }
    __syncthreads();
    for (int p = tid; p < cnt; p += 256) {
        int d = (int)(unsigned)pairs[beg + p];
        atomicAdd(&ldeg[d - node0], 1);
    }
    __syncthreads();
    // exclusive scan ldeg (wave 0)
    if (tid < 64) {
        int per = bnodes >> 6;
        int b0 = tid * per, s = 0;
        for (int j = 0; j < per; ++j) s += ldeg[b0 + j];
        int sc = s;
        for (int o = 1; o < 64; o <<= 1) { int u = __shfl_up(sc, o); if (tid >= o) sc += u; }
        int ex = sc - s;
        for (int j = 0; j < per; ++j) { lrow[b0 + j] = ex; ex += ldeg[b0 + j]; }
    }
    __syncthreads();
    for (int i = tid; i < bnodes; i += 256) {
        int node = node0 + i;
        if (node < n) {
            row_ptr[node] = beg + lrow[i];
            dinv[node] = rsqrtf((float)(ldeg[i] + 1));   // +1 self loop
        }
    }
    if (cnt <= CAP) {
        for (int p = tid; p < cnt; p += 256) {
            unsigned long long pr = pairs[beg + p];
            int d = (int)(unsigned)pr, s = (int)(pr >> 32);
            int l = d - node0;
            int r = atomicAdd(&lcur[l], 1);
            sstage[lrow[l] + r] = s;
        }
        __syncthreads();
        for (int p = tid; p < cnt; p += 256) srcs[beg + p] = sstage[p];
    } else {
        // pathological bucket: direct (slow but correct)
        for (int p = tid; p < cnt; p += 256) {
            unsigned long long pr = pairs[beg + p];
            int d = (int)(unsigned)pr, s = (int)(pr >> 32);
            int l = d - node0;
            int r = atomicAdd(&lcur[l], 1);
            srcs[beg + lrow[l] + r] = s;
        }
    }
}

// ---------- GEMM1: h = x @ W1   (N x 64) @ (64 x 64) ----------
__global__ __launch_bounds__(256) void k_gemm1(const float* __restrict__ x,
                                               const float* __restrict__ W,
                                               float* __restrict__ h, int n) {
    __shared__ float Ws[64 * 64];
    __shared__ float xs[4][64];
    int tid = threadIdx.x;
#pragma unroll
    for (int i = 0; i < 16; ++i) Ws[tid + i * 256] = W[tid + i * 256];
    int r = tid >> 6, c = tid & 63;
    int row = blockIdx.x * 4 + r;
    xs[r][c] = (row < n) ? x[row * 64 + c] : 0.0f;
    __syncthreads();
    float acc = 0.0f;
#pragma unroll
    for (int k = 0; k < 64; k += 4) {
        float4 xv = *(const float4*)&xs[r][k];
        acc = fmaf(xv.x, Ws[(k + 0) * 64 + c], acc);
        acc = fmaf(xv.y, Ws[(k + 1) * 64 + c], acc);
        acc = fmaf(xv.z, Ws[(k + 2) * 64 + c], acc);
        acc = fmaf(xv.w, Ws[(k + 3) * 64 + c], acc);
    }
    if (row < n) h[row * 64 + c] = acc;
}

// ---------- CSR gather-aggregate layer 1: one wave per node, lane = feature ----------
__global__ __launch_bounds__(256) void k_gather(const float* __restrict__ h,
                                                const int* __restrict__ srcs,
                                                const int* __restrict__ row_ptr,
                                                const float* __restrict__ dinv,
                                                const float* __restrict__ b,
                                                float* __restrict__ out, int n) {
    int node = (int)(((long long)blockIdx.x * 256 + threadIdx.x) >> 6);
    int lane = threadIdx.x & 63;
    if (node >= n) return;
    float di = dinv[node];
    float acc = b[lane] + h[(long long)node * 64 + lane] * di * di;
    int e = row_ptr[node], end = row_ptr[node + 1];
    for (; e + 3 < end; e += 4) {
        int s0 = srcs[e], s1 = srcs[e + 1], s2 = srcs[e + 2], s3 = srcs[e + 3];
        float v0 = h[(long long)s0 * 64 + lane];
        float v1 = h[(long long)s1 * 64 + lane];
        float v2 = h[(long long)s2 * 64 + lane];
        float v3 = h[(long long)s3 * 64 + lane];
        float n0 = dinv[s0] * di, n1 = dinv[s1] * di, n2 = dinv[s2] * di, n3 = dinv[s3] * di;
        acc = fmaf(v0, n0, acc);
        acc = fmaf(v1, n1, acc);
        acc = fmaf(v2, n2, acc);
        acc = fmaf(v3, n3, acc);
    }
    for (; e < end; ++e) {
        int s0 = srcs[e];
        acc = fmaf(h[(long long)s0 * 64 + lane], dinv[s0] * di, acc);
    }
    out[(long long)node * 64 + lane] = acc;
}

// ---------- layer-2 transform: t = relu(agg1) @ W2  (N x 40) ----------
__global__ __launch_bounds__(256) void k_trans2(const float* __restrict__ agg,
                                                const float* __restrict__ W2,
                                                float* __restrict__ t, int n,
                                                int nwaves) {
    int wid = blockIdx.x * 4 + (threadIdx.x >> 6);
    int lane = threadIdx.x & 63;
    float wcol[64];
#pragma unroll
    for (int k = 0; k < 64; ++k)
        wcol[k] = (lane < 40) ? W2[k * 40 + lane] : 0.0f;
    for (int node = wid; node < n; node += nwaves) {
        int node_u = __builtin_amdgcn_readfirstlane(node);
        const float* arow = agg + (size_t)node_u * 64;
        float acc = 0.0f;
#pragma unroll
        for (int k4 = 0; k4 < 16; ++k4) {
            float4 a = *(const float4*)(arow + k4 * 4);   // wave-uniform -> s_load
            acc = fmaf(fmaxf(a.x, 0.0f), wcol[k4 * 4 + 0], acc);
            acc = fmaf(fmaxf(a.y, 0.0f), wcol[k4 * 4 + 1], acc);
            acc = fmaf(fmaxf(a.z, 0.0f), wcol[k4 * 4 + 2], acc);
            acc = fmaf(fmaxf(a.w, 0.0f), wcol[k4 * 4 + 3], acc);
        }
        if (lane < 40) t[(size_t)node_u * 40 + lane] = acc;
    }
}

// ---------- layer-2 gather (40-wide) + bias + log_softmax ----------
__global__ __launch_bounds__(256) void k_gather40(const float* __restrict__ t,
                                                  const int* __restrict__ srcs,
                                                  const int* __restrict__ row_ptr,
                                                  const float* __restrict__ dinv,
                                                  const float* __restrict__ b2,
                                                  float* __restrict__ out, int n) {
    int node = (int)(((long long)blockIdx.x * 256 + threadIdx.x) >> 6);
    int lane = threadIdx.x & 63;
    if (node >= n) return;
    bool act = lane < 40;
    float di = dinv[node];
    float acc = act ? (b2[lane] + t[(long long)node * 40 + lane] * di * di) : 0.0f;
    int e = row_ptr[node], end = row_ptr[node + 1];
    for (; e + 3 < end; e += 4) {
        int s0 = srcs[e], s1 = srcs[e + 1], s2 = srcs[e + 2], s3 = srcs[e + 3];
        float v0 = act ? t[(long long)s0 * 40 + lane] : 0.0f;
        float v1 = act ? t[(long long)s1 * 40 + lane] : 0.0f;
        float v2 = act ? t[(long long)s2 * 40 + lane] : 0.0f;
        float v3 = act ? t[(long long)s3 * 40 + lane] : 0.0f;
        float n0 = dinv[s0] * di, n1 = dinv[s1] * di, n2 = dinv[s2] * di, n3 = dinv[s3] * di;
        acc = fmaf(v0, n0, acc);
        acc = fmaf(v1, n1, acc);
        acc = fmaf(v2, n2, acc);
        acc = fmaf(v3, n3, acc);
    }
    for (; e < end; ++e) {
        int s0 = srcs[e];
        float v0 = act ? t[(long long)s0 * 40 + lane] : 0.0f;
        acc = fmaf(v0, dinv[s0] * di, acc);
    }
    float v = act ? acc : -INFINITY;
    float m = v;
    for (int o = 32; o; o >>= 1) m = fmaxf(m, __shfl_xor(m, o));
    float ex = act ? expf(v - m) : 0.0f;
    float s = ex;
    for (int o = 32; o; o >>= 1) s += __shfl_xor(s, o);
    float r = v - m - logf(s);
    if (act) out[(long long)node * 40 + lane] = r;
}

extern "C" void kernel_launch(void* const* d_in, const int* in_sizes, int n_in,
                              void* d_out, int out_size, void* d_ws, size_t ws_size,
                              hipStream_t stream) {
    const float* x  = (const float*)d_in[0];
    const int*   ei = (const int*)d_in[1];
    const float* W1 = (const float*)d_in[2];
    const float* b1 = (const float*)d_in[3];
    const float* W2 = (const float*)d_in[4];
    const float* b2 = (const float*)d_in[5];

    const int N = in_sizes[0] / F1;      // 100000
    const int E = in_sizes[1] / 2;       // 1600000
    const int* src = ei;
    const int* dst = ei + E;

    // bucket shift: smallest bsh with ceil(N / 2^bsh) <= NB (bsh=8 for N=100000)
    int bsh = 8;
    while ((((N - 1) >> bsh) + 1) > NB) ++bsh;
    const int NBu = ((N - 1) >> bsh) + 1;

    // workspace layout (pairs first: 8-byte aligned)
    unsigned long long* pairs = (unsigned long long*)d_ws;       // E
    float* bufA    = (float*)(pairs + E);                        // N*64 (h1, later t=N*40)
    float* bufB    = bufA + (size_t)N * F1;                      // N*64 (agg1)
    int*   srcs    = (int*)(bufB + (size_t)N * F1);              // E
    int*   row_ptr = srcs + E;                                   // N+1
    float* dinv    = (float*)(row_ptr + N + 1);                  // N
    int*   bcnt    = (int*)(dinv + N);                           // NB
    int*   bptr    = bcnt + NB;                                  // NB+1
    int*   gcur    = bptr + NB + 1;                              // NB
    float* outp    = (float*)d_out;                              // N*40

    const int B = 256;
    const int GT = (E + TILE - 1) / TILE;   // 391

    // --- CSR build (bucketed, no random global atomics/scatters) ---
    k_zero_int<<<(NB + B - 1) / B, B, 0, stream>>>(bcnt, NB);
    k_bhist<<<GT, B, 0, stream>>>(dst, bcnt, E, bsh);
    k_bscan<<<1, NB, 0, stream>>>(bcnt, bptr, gcur, row_ptr, N, E);
    k_bscatter<<<GT, B, 0, stream>>>(src, dst, gcur, pairs, E, bsh);
    k_bfinal<<<NBu, B, 0, stream>>>(pairs, bptr, srcs, row_ptr, dinv, N, bsh);

    // --- layer 1: GEMM then gather-aggregate (+b1) ---
    k_gemm1<<<(N + 3) / 4, B, 0, stream>>>(x, W1, bufA, N);
    k_gather<<<(N + 3) / 4, B, 0, stream>>>(bufA, srcs, row_ptr, dinv, b1, bufB, N);

    // --- layer 2: transform first, then 40-wide gather + bias + log_softmax ---
    const int TB = 2048;
    k_trans2<<<TB, B, 0, stream>>>(bufB, W2, bufA, N, TB * 4);
    k_gather40<<<(N + 3) / 4, B, 0, stream>>>(bufA, srcs, row_ptr, dinv, b2, outp, N);
}

// Round 7
// 364.010 us; speedup vs baseline: 1.5361x; 1.0927x over previous
//
#include <hip/hip_runtime.h>
#include <math.h>

#define F1 64   // input/hidden features
#define F2 40   // classes
#define NB 512      // buckets for CSR build
#define TILE 4096   // edges per k_bscatter/k_bhist block (256 thr x 16)
#define CAP 12288   // max LDS-staged edges per bucket in k_bfinal (48 KB)

// ---------- bf16 helpers ----------
__device__ inline unsigned short f2bf(float f) {
    unsigned u = __float_as_uint(f);
    unsigned r = (u + 0x7FFFu + ((u >> 16) & 1u)) >> 16;   // RNE
    return (unsigned short)r;
}
__device__ inline float bf_lo(unsigned u) { return __uint_as_float(u << 16); }
__device__ inline float bf_hi(unsigned u) { return __uint_as_float(u & 0xFFFF0000u); }

// ---------- utility ----------
__global__ void k_zero_int(int* p, int n) {
    int i = blockIdx.x * blockDim.x + threadIdx.x;
    if (i < n) p[i] = 0;
}

// ---------- pass 1a: bucket histogram (coalesced reads, LDS hist) ----------
__global__ __launch_bounds__(256) void k_bhist(const int* __restrict__ dst,
                                               int* __restrict__ bcnt, int e, int bsh) {
    __shared__ int h[NB];
    int tid = threadIdx.x;
    for (int i = tid; i < NB; i += 256) h[i] = 0;
    __syncthreads();
    int base = blockIdx.x * TILE;
    int lim = min(base + TILE, e);
    for (int i = base + tid; i < lim; i += 256) atomicAdd(&h[dst[i] >> bsh], 1);
    __syncthreads();
    for (int i = tid; i < NB; i += 256) if (h[i]) atomicAdd(&bcnt[i], h[i]);
}

// ---------- pass 1b: scan of bucket counts (single block) ----------
__global__ __launch_bounds__(NB) void k_bscan(const int* __restrict__ bcnt,
                                              int* __restrict__ bptr, int* __restrict__ gcur,
                                              int* __restrict__ row_ptr, int n, int e) {
    __shared__ int sh[NB];
    int t = threadIdx.x;
    sh[t] = bcnt[t];
    __syncthreads();
    for (int off = 1; off < NB; off <<= 1) {
        int v = (t >= off) ? sh[t - off] : 0;
        __syncthreads();
        sh[t] += v;
        __syncthreads();
    }
    int ex = t ? sh[t - 1] : 0;
    bptr[t] = ex;
    gcur[t] = ex;
    if (t == NB - 1) bptr[NB] = sh[NB - 1];
    if (t == 0) row_ptr[n] = e;   // global total
}

// ---------- pass 1c: bucket the (src,dst) pairs, LDS-reordered coalesced writes ----------
__global__ __launch_bounds__(256) void k_bscatter(const int* __restrict__ src,
                                                  const int* __restrict__ dst,
                                                  int* gcur,
                                                  unsigned long long* __restrict__ pairs,
                                                  int e, int bsh) {
    __shared__ int lhist[NB];
    __shared__ int lstart[NB];
    __shared__ int delta[NB];
    __shared__ unsigned long long stage[TILE];
    int tid = threadIdx.x;
    for (int i = tid; i < NB; i += 256) lhist[i] = 0;
    __syncthreads();
    int base = blockIdx.x * TILE;
    int cnt = min(TILE, e - base);
    int sA[16], dA[16], rA[16];
#pragma unroll
    for (int k = 0; k < 16; ++k) {
        int i = base + k * 256 + tid;
        if (i < e) {
            sA[k] = src[i];
            dA[k] = dst[i];
            rA[k] = atomicAdd(&lhist[dA[k] >> bsh], 1);
        }
    }
    __syncthreads();
    if (tid < 64) {
        int v[8];
        int b0 = tid * 8, s = 0;
#pragma unroll
        for (int j = 0; j < 8; ++j) { v[j] = lhist[b0 + j]; s += v[j]; }
        int sc = s;
        for (int o = 1; o < 64; o <<= 1) { int u = __shfl_up(sc, o); if (tid >= o) sc += u; }
        int ex = sc - s;
#pragma unroll
        for (int j = 0; j < 8; ++j) { lstart[b0 + j] = ex; ex += v[j]; }
    }
    __syncthreads();
    for (int i = tid; i < NB; i += 256) {
        int c = lhist[i];
        if (c) delta[i] = atomicAdd(&gcur[i], c) - lstart[i];
    }
    __syncthreads();
#pragma unroll
    for (int k = 0; k < 16; ++k) {
        int i = base + k * 256 + tid;
        if (i < e) {
            int b = dA[k] >> bsh;
            stage[lstart[b] + rA[k]] =
                ((unsigned long long)(unsigned)sA[k] << 32) | (unsigned)dA[k];
        }
    }
    __syncthreads();
    for (int p = tid; p < cnt; p += 256) {
        unsigned long long pr = stage[p];
        int b = ((int)(unsigned)pr) >> bsh;
        pairs[delta[b] + p] = pr;
    }
}

// ---------- pass 2: per-bucket CSR finalize (row_ptr, dinv, srcs) ----------
__global__ __launch_bounds__(256) void k_bfinal(const unsigned long long* __restrict__ pairs,
                                                const int* __restrict__ bptr,
                                                int* __restrict__ srcs,
                                                int* __restrict__ row_ptr,
                                                float* __restrict__ dinv,
                                                int n, int bsh) {
    __shared__ int ldeg[NB];
    __shared__ int lrow[NB];
    __shared__ int lcur[NB];
    __shared__ int sstage[CAP];
    int b = blockIdx.x, tid = threadIdx.x;
    int beg = bptr[b], end = bptr[b + 1];
    int cnt = end - beg;
    int node0 = b << bsh;
    int bnodes = 1 << bsh;
    for (int i = tid; i < bnodes; i += 256) { ldeg[i] = 0; lcur[i] = 0; }
    __syncthreads();
    for (int p = tid; p < cnt; p += 256) {
        int d = (int)(unsigned)pairs[beg + p];
        atomicAdd(&ldeg[d - node0], 1);
    }
    __syncthreads();
    if (tid < 64) {
        int per = bnodes >> 6;
        int b0 = tid * per, s = 0;
        for (int j = 0; j < per; ++j) s += ldeg[b0 + j];
        int sc = s;
        for (int o = 1; o < 64; o <<= 1) { int u = __shfl_up(sc, o); if (tid >= o) sc += u; }
        int ex = sc - s;
        for (int j = 0; j < per; ++j) { lrow[b0 + j] = ex; ex += ldeg[b0 + j]; }
    }
    __syncthreads();
    for (int i = tid; i < bnodes; i += 256) {
        int node = node0 + i;
        if (node < n) {
            row_ptr[node] = beg + lrow[i];
            dinv[node] = rsqrtf((float)(ldeg[i] + 1));   // +1 self loop
        }
    }
    if (cnt <= CAP) {
        for (int p = tid; p < cnt; p += 256) {
            unsigned long long pr = pairs[beg + p];
            int d = (int)(unsigned)pr, s = (int)(pr >> 32);
            int l = d - node0;
            int r = atomicAdd(&lcur[l], 1);
            sstage[lrow[l] + r] = s;
        }
        __syncthreads();
        for (int p = tid; p < cnt; p += 256) srcs[beg + p] = sstage[p];
    } else {
        for (int p = tid; p < cnt; p += 256) {
            unsigned long long pr = pairs[beg + p];
            int d = (int)(unsigned)pr, s = (int)(pr >> 32);
            int l = d - node0;
            int r = atomicAdd(&lcur[l], 1);
            srcs[beg + lrow[l] + r] = s;
        }
    }
}

// ---------- GEMM1: h = x @ W1  (N x 64) @ (64 x 64), bf16 output ----------
__global__ __launch_bounds__(256) void k_gemm1(const float* __restrict__ x,
                                               const float* __restrict__ W,
                                               unsigned short* __restrict__ h, int n) {
    __shared__ float Ws[64 * 64];
    __shared__ float xs[4][64];
    int tid = threadIdx.x;
#pragma unroll
    for (int i = 0; i < 16; ++i) Ws[tid + i * 256] = W[tid + i * 256];
    int r = tid >> 6, c = tid & 63;
    int row = blockIdx.x * 4 + r;
    xs[r][c] = (row < n) ? x[row * 64 + c] : 0.0f;
    __syncthreads();
    float acc = 0.0f;
#pragma unroll
    for (int k = 0; k < 64; k += 4) {
        float4 xv = *(const float4*)&xs[r][k];
        acc = fmaf(xv.x, Ws[(k + 0) * 64 + c], acc);
        acc = fmaf(xv.y, Ws[(k + 1) * 64 + c], acc);
        acc = fmaf(xv.z, Ws[(k + 2) * 64 + c], acc);
        acc = fmaf(xv.w, Ws[(k + 3) * 64 + c], acc);
    }
    if (row < n) h[row * 64 + c] = f2bf(acc);
}

// ---------- layer-1 gather: wave per node, 2 edges/iter, bf16x2 per lane ----------
// h: N x 32 uints (packed bf16 pairs). out: fp32 N x 64 (agg1, +b1).
__global__ __launch_bounds__(256) void k_gather(const unsigned* __restrict__ h,
                                                const int* __restrict__ srcs,
                                                const int* __restrict__ row_ptr,
                                                const float* __restrict__ dinv,
                                                const float* __restrict__ b,
                                                float* __restrict__ out, int n) {
    int node = (int)(((long long)blockIdx.x * 256 + threadIdx.x) >> 6);
    int lane = threadIdx.x & 63;
    if (node >= n) return;
    int slot = lane >> 5, j = lane & 31;
    float di = dinv[node];
    float2 acc = make_float2(0.0f, 0.0f);
    if (slot == 0) {
        unsigned u = h[node * 32 + j];
        acc.x = b[2 * j]     + bf_lo(u) * di * di;
        acc.y = b[2 * j + 1] + bf_hi(u) * di * di;
    }
    int e0 = row_ptr[node], cnt = row_ptr[node + 1] - e0;
    int p = slot;
    for (; p + 2 < cnt; p += 4) {
        int s0 = srcs[e0 + p], s1 = srcs[e0 + p + 2];
        float n0 = dinv[s0] * di, n1 = dinv[s1] * di;
        unsigned u0 = h[s0 * 32 + j];
        unsigned u1 = h[s1 * 32 + j];
        acc.x = fmaf(bf_lo(u0), n0, acc.x);
        acc.y = fmaf(bf_hi(u0), n0, acc.y);
        acc.x = fmaf(bf_lo(u1), n1, acc.x);
        acc.y = fmaf(bf_hi(u1), n1, acc.y);
    }
    if (p < cnt) {
        int s0 = srcs[e0 + p];
        float n0 = dinv[s0] * di;
        unsigned u0 = h[s0 * 32 + j];
        acc.x = fmaf(bf_lo(u0), n0, acc.x);
        acc.y = fmaf(bf_hi(u0), n0, acc.y);
    }
    acc.x += __shfl_xor(acc.x, 32);
    acc.y += __shfl_xor(acc.y, 32);
    if (slot == 0) *(float2*)&out[(long long)node * 64 + 2 * j] = acc;
}

// ---------- layer-2 transform: t = relu(agg1) @ W2  (N x 40), bf16 output ----------
__global__ __launch_bounds__(256) void k_trans2(const float* __restrict__ agg,
                                                const float* __restrict__ W2,
                                                unsigned short* __restrict__ t, int n,
                                                int nwaves) {
    int wid = blockIdx.x * 4 + (threadIdx.x >> 6);
    int lane = threadIdx.x & 63;
    float wcol[64];
#pragma unroll
    for (int k = 0; k < 64; ++k)
        wcol[k] = (lane < 40) ? W2[k * 40 + lane] : 0.0f;
    for (int node = wid; node < n; node += nwaves) {
        int node_u = __builtin_amdgcn_readfirstlane(node);
        const float* arow = agg + (size_t)node_u * 64;
        float acc = 0.0f;
#pragma unroll
        for (int k4 = 0; k4 < 16; ++k4) {
            float4 a = *(const float4*)(arow + k4 * 4);   // wave-uniform -> s_load
            acc = fmaf(fmaxf(a.x, 0.0f), wcol[k4 * 4 + 0], acc);
            acc = fmaf(fmaxf(a.y, 0.0f), wcol[k4 * 4 + 1], acc);
            acc = fmaf(fmaxf(a.z, 0.0f), wcol[k4 * 4 + 2], acc);
            acc = fmaf(fmaxf(a.w, 0.0f), wcol[k4 * 4 + 3], acc);
        }
        if (lane < 40) t[(size_t)node_u * 40 + lane] = f2bf(acc);
    }
}

// ---------- layer-2 gather (bf16, 2 edges/iter) + bias + log_softmax ----------
// t: N x 20 uints (packed bf16 pairs).
__global__ __launch_bounds__(256) void k_gather40(const unsigned* __restrict__ t,
                                                  const int* __restrict__ srcs,
                                                  const int* __restrict__ row_ptr,
                                                  const float* __restrict__ dinv,
                                                  const float* __restrict__ b2,
                                                  float* __restrict__ out, int n) {
    int node = (int)(((long long)blockIdx.x * 256 + threadIdx.x) >> 6);
    int lane = threadIdx.x & 63;
    if (node >= n) return;
    int slot = lane >> 5, j = lane & 31;
    bool act = j < 20;
    float di = dinv[node];
    float2 acc = make_float2(0.0f, 0.0f);
    if (slot == 0 && act) {
        unsigned u = t[node * 20 + j];
        acc.x = b2[2 * j]     + bf_lo(u) * di * di;
        acc.y = b2[2 * j + 1] + bf_hi(u) * di * di;
    }
    int e0 = row_ptr[node], cnt = row_ptr[node + 1] - e0;
    int p = slot;
    for (; p + 2 < cnt; p += 4) {
        int s0 = srcs[e0 + p], s1 = srcs[e0 + p + 2];
        float n0 = dinv[s0] * di, n1 = dinv[s1] * di;
        if (act) {
            unsigned u0 = t[s0 * 20 + j];
            unsigned u1 = t[s1 * 20 + j];
            acc.x = fmaf(bf_lo(u0), n0, acc.x);
            acc.y = fmaf(bf_hi(u0), n0, acc.y);
            acc.x = fmaf(bf_lo(u1), n1, acc.x);
            acc.y = fmaf(bf_hi(u1), n1, acc.y);
        }
    }
    if (p < cnt) {
        int s0 = srcs[e0 + p];
        float n0 = dinv[s0] * di;
        if (act) {
            unsigned u0 = t[s0 * 20 + j];
            acc.x = fmaf(bf_lo(u0), n0, acc.x);
            acc.y = fmaf(bf_hi(u0), n0, acc.y);
        }
    }
    acc.x += __shfl_xor(acc.x, 32);
    acc.y += __shfl_xor(acc.y, 32);
    // log_softmax over 40 classes (held as float2 by j<20 lanes, duplicated across slots)
    float m = act ? fmaxf(acc.x, acc.y) : -INFINITY;
    for (int o = 32; o; o >>= 1) m = fmaxf(m, __shfl_xor(m, o));
    float ex = (act && slot == 0) ? (expf(acc.x - m) + expf(acc.y - m)) : 0.0f;
    float s = ex;
    for (int o = 32; o; o >>= 1) s += __shfl_xor(s, o);
    float ls = logf(s);
    if (slot == 0 && act) {
        float2 r = make_float2(acc.x - m - ls, acc.y - m - ls);
        *(float2*)&out[(long long)node * 40 + 2 * j] = r;
    }
}

extern "C" void kernel_launch(void* const* d_in, const int* in_sizes, int n_in,
                              void* d_out, int out_size, void* d_ws, size_t ws_size,
                              hipStream_t stream) {
    const float* x  = (const float*)d_in[0];
    const int*   ei = (const int*)d_in[1];
    const float* W1 = (const float*)d_in[2];
    const float* b1 = (const float*)d_in[3];
    const float* W2 = (const float*)d_in[4];
    const float* b2 = (const float*)d_in[5];

    const int N = in_sizes[0] / F1;      // 100000
    const int E = in_sizes[1] / 2;       // 1600000
    const int* src = ei;
    const int* dst = ei + E;

    int bsh = 8;
    while ((((N - 1) >> bsh) + 1) > NB) ++bsh;
    const int NBu = ((N - 1) >> bsh) + 1;

    // workspace layout (8-byte aligned first)
    unsigned long long* pairs = (unsigned long long*)d_ws;        // E
    float* bufB    = (float*)(pairs + E);                         // N*64 fp32 (agg1)
    unsigned* h1b  = (unsigned*)(bufB + (size_t)N * F1);          // N*32 uints (bf16 h1)
    unsigned* tb   = h1b + (size_t)N * 32;                        // N*20 uints (bf16 t)
    int*   srcs    = (int*)(tb + (size_t)N * 20);                 // E
    int*   row_ptr = srcs + E;                                    // N+1
    float* dinv    = (float*)(row_ptr + N + 1);                   // N
    int*   bcnt    = (int*)(dinv + N);                            // NB
    int*   bptr    = bcnt + NB;                                   // NB+1
    int*   gcur    = bptr + NB + 1;                               // NB
    float* outp    = (float*)d_out;                               // N*40

    const int B = 256;
    const int GT = (E + TILE - 1) / TILE;

    // --- CSR build (bucketed) ---
    k_zero_int<<<(NB + B - 1) / B, B, 0, stream>>>(bcnt, NB);
    k_bhist<<<GT, B, 0, stream>>>(dst, bcnt, E, bsh);
    k_bscan<<<1, NB, 0, stream>>>(bcnt, bptr, gcur, row_ptr, N, E);
    k_bscatter<<<GT, B, 0, stream>>>(src, dst, gcur, pairs, E, bsh);
    k_bfinal<<<NBu, B, 0, stream>>>(pairs, bptr, srcs, row_ptr, dinv, N, bsh);

    // --- layer 1: GEMM (bf16 out) then bf16 gather-aggregate (+b1) ---
    k_gemm1<<<(N + 3) / 4, B, 0, stream>>>(x, W1, (unsigned short*)h1b, N);
    k_gather<<<(N + 3) / 4, B, 0, stream>>>(h1b, srcs, row_ptr, dinv, b1, bufB, N);

    // --- layer 2: transform (bf16 out), then bf16 gather + bias + log_softmax ---
    const int TB = 2048;
    k_trans2<<<TB, B, 0, stream>>>(bufB, W2, (unsigned short*)tb, N, TB * 4);
    k_gather40<<<(N + 3) / 4, B, 0, stream>>>(tb, srcs, row_ptr, dinv, b2, outp, N);
}

// Round 8
// 359.588 us; speedup vs baseline: 1.5550x; 1.0123x over previous
//
#include <hip/hip_runtime.h>
#include <math.h>

#define F1 64   // input/hidden features
#define F2 40   // classes
#define NB 512      // buckets for CSR build
#define TILE 4096   // edges per k_bscatter/k_bhist block (256 thr x 16)
#define CAP 12288   // max LDS-staged edges per bucket in k_bfinal (48 KB)

// ---------- bf16 helpers ----------
__device__ inline unsigned short f2bf(float f) {
    unsigned u = __float_as_uint(f);
    unsigned r = (u + 0x7FFFu + ((u >> 16) & 1u)) >> 16;   // RNE
    return (unsigned short)r;
}
__device__ inline float bf_lo(unsigned u) { return __uint_as_float(u << 16); }
__device__ inline float bf_hi(unsigned u) { return __uint_as_float(u & 0xFFFF0000u); }

// ---------- utility ----------
__global__ void k_zero_int(int* p, int n) {
    int i = blockIdx.x * blockDim.x + threadIdx.x;
    if (i < n) p[i] = 0;
}

// ---------- pass 1a: bucket histogram ----------
__global__ __launch_bounds__(256) void k_bhist(const int* __restrict__ dst,
                                               int* __restrict__ bcnt, int e, int bsh) {
    __shared__ int h[NB];
    int tid = threadIdx.x;
    for (int i = tid; i < NB; i += 256) h[i] = 0;
    __syncthreads();
    int base = blockIdx.x * TILE;
    int lim = min(base + TILE, e);
    for (int i = base + tid; i < lim; i += 256) atomicAdd(&h[dst[i] >> bsh], 1);
    __syncthreads();
    for (int i = tid; i < NB; i += 256) if (h[i]) atomicAdd(&bcnt[i], h[i]);
}

// ---------- pass 1b: scan of bucket counts ----------
__global__ __launch_bounds__(NB) void k_bscan(const int* __restrict__ bcnt,
                                              int* __restrict__ bptr, int* __restrict__ gcur,
                                              int* __restrict__ row_ptr, int n, int e) {
    __shared__ int sh[NB];
    int t = threadIdx.x;
    sh[t] = bcnt[t];
    __syncthreads();
    for (int off = 1; off < NB; off <<= 1) {
        int v = (t >= off) ? sh[t - off] : 0;
        __syncthreads();
        sh[t] += v;
        __syncthreads();
    }
    int ex = t ? sh[t - 1] : 0;
    bptr[t] = ex;
    gcur[t] = ex;
    if (t == NB - 1) bptr[NB] = sh[NB - 1];
    if (t == 0) row_ptr[n] = e;
}

// ---------- pass 1c: bucket (src,dst) pairs ----------
__global__ __launch_bounds__(256) void k_bscatter(const int* __restrict__ src,
                                                  const int* __restrict__ dst,
                                                  int* gcur,
                                                  unsigned long long* __restrict__ pairs,
                                                  int e, int bsh) {
    __shared__ int lhist[NB];
    __shared__ int lstart[NB];
    __shared__ int delta[NB];
    __shared__ unsigned long long stage[TILE];
    int tid = threadIdx.x;
    for (int i = tid; i < NB; i += 256) lhist[i] = 0;
    __syncthreads();
    int base = blockIdx.x * TILE;
    int cnt = min(TILE, e - base);
    int sA[16], dA[16], rA[16];
#pragma unroll
    for (int k = 0; k < 16; ++k) {
        int i = base + k * 256 + tid;
        if (i < e) {
            sA[k] = src[i];
            dA[k] = dst[i];
            rA[k] = atomicAdd(&lhist[dA[k] >> bsh], 1);
        }
    }
    __syncthreads();
    if (tid < 64) {
        int v[8];
        int b0 = tid * 8, s = 0;
#pragma unroll
        for (int j = 0; j < 8; ++j) { v[j] = lhist[b0 + j]; s += v[j]; }
        int sc = s;
        for (int o = 1; o < 64; o <<= 1) { int u = __shfl_up(sc, o); if (tid >= o) sc += u; }
        int ex = sc - s;
#pragma unroll
        for (int j = 0; j < 8; ++j) { lstart[b0 + j] = ex; ex += v[j]; }
    }
    __syncthreads();
    for (int i = tid; i < NB; i += 256) {
        int c = lhist[i];
        if (c) delta[i] = atomicAdd(&gcur[i], c) - lstart[i];
    }
    __syncthreads();
#pragma unroll
    for (int k = 0; k < 16; ++k) {
        int i = base + k * 256 + tid;
        if (i < e) {
            int b = dA[k] >> bsh;
            stage[lstart[b] + rA[k]] =
                ((unsigned long long)(unsigned)sA[k] << 32) | (unsigned)dA[k];
        }
    }
    __syncthreads();
    for (int p = tid; p < cnt; p += 256) {
        unsigned long long pr = stage[p];
        int b = ((int)(unsigned)pr) >> bsh;
        pairs[delta[b] + p] = pr;
    }
}

// ---------- pass 2: per-bucket CSR finalize ----------
__global__ __launch_bounds__(256) void k_bfinal(const unsigned long long* __restrict__ pairs,
                                                const int* __restrict__ bptr,
                                                int* __restrict__ srcs,
                                                int* __restrict__ row_ptr,
                                                float* __restrict__ dinv,
                                                int n, int bsh) {
    __shared__ int ldeg[NB];
    __shared__ int lrow[NB];
    __shared__ int lcur[NB];
    __shared__ int sstage[CAP];
    int b = blockIdx.x, tid = threadIdx.x;
    int beg = bptr[b], end = bptr[b + 1];
    int cnt = end - beg;
    int node0 = b << bsh;
    int bnodes = 1 << bsh;
    for (int i = tid; i < bnodes; i += 256) { ldeg[i] = 0; lcur[i] = 0; }
    __syncthreads();
    for (int p = tid; p < cnt; p += 256) {
        int d = (int)(unsigned)pairs[beg + p];
        atomicAdd(&ldeg[d - node0], 1);
    }
    __syncthreads();
    if (tid < 64) {
        int per = bnodes >> 6;
        int b0 = tid * per, s = 0;
        for (int j = 0; j < per; ++j) s += ldeg[b0 + j];
        int sc = s;
        for (int o = 1; o < 64; o <<= 1) { int u = __shfl_up(sc, o); if (tid >= o) sc += u; }
        int ex = sc - s;
        for (int j = 0; j < per; ++j) { lrow[b0 + j] = ex; ex += ldeg[b0 + j]; }
    }
    __syncthreads();
    for (int i = tid; i < bnodes; i += 256) {
        int node = node0 + i;
        if (node < n) {
            row_ptr[node] = beg + lrow[i];
            dinv[node] = rsqrtf((float)(ldeg[i] + 1));
        }
    }
    if (cnt <= CAP) {
        for (int p = tid; p < cnt; p += 256) {
            unsigned long long pr = pairs[beg + p];
            int d = (int)(unsigned)pr, s = (int)(pr >> 32);
            int l = d - node0;
            int r = atomicAdd(&lcur[l], 1);
            sstage[lrow[l] + r] = s;
        }
        __syncthreads();
        for (int p = tid; p < cnt; p += 256) srcs[beg + p] = sstage[p];
    } else {
        for (int p = tid; p < cnt; p += 256) {
            unsigned long long pr = pairs[beg + p];
            int d = (int)(unsigned)pr, s = (int)(pr >> 32);
            int l = d - node0;
            int r = atomicAdd(&lcur[l], 1);
            srcs[beg + lrow[l] + r] = s;
        }
    }
}

// ---------- pass 3: per-edge (src, norm) pack — removes dinv from gather loops ----------
__global__ __launch_bounds__(256) void k_en(const int* __restrict__ srcs,
                                            const int* __restrict__ row_ptr,
                                            const float* __restrict__ dinv,
                                            int2* __restrict__ en, int n) {
    int node = (int)(((long long)blockIdx.x * 256 + threadIdx.x) >> 6);
    int lane = threadIdx.x & 63;
    if (node >= n) return;
    float di = dinv[node];
    int e0 = row_ptr[node], e1 = row_ptr[node + 1];
    for (int p = e0 + lane; p < e1; p += 64) {
        int s = srcs[p];
        en[p] = make_int2(s, __float_as_int(dinv[s] * di));
    }
}

// ---------- GEMM1: h = x @ W1, bf16 output ----------
__global__ __launch_bounds__(256) void k_gemm1(const float* __restrict__ x,
                                               const float* __restrict__ W,
                                               unsigned short* __restrict__ h, int n) {
    __shared__ float Ws[64 * 64];
    __shared__ float xs[4][64];
    int tid = threadIdx.x;
#pragma unroll
    for (int i = 0; i < 16; ++i) Ws[tid + i * 256] = W[tid + i * 256];
    int r = tid >> 6, c = tid & 63;
    int row = blockIdx.x * 4 + r;
    xs[r][c] = (row < n) ? x[row * 64 + c] : 0.0f;
    __syncthreads();
    float acc = 0.0f;
#pragma unroll
    for (int k = 0; k < 64; k += 4) {
        float4 xv = *(const float4*)&xs[r][k];
        acc = fmaf(xv.x, Ws[(k + 0) * 64 + c], acc);
        acc = fmaf(xv.y, Ws[(k + 1) * 64 + c], acc);
        acc = fmaf(xv.z, Ws[(k + 2) * 64 + c], acc);
        acc = fmaf(xv.w, Ws[(k + 3) * 64 + c], acc);
    }
    if (row < n) h[row * 64 + c] = f2bf(acc);
}

// ---------- layer-1 gather: wave/node, 2 slots x 4-edge unroll, bf16x2/lane ----------
__global__ __launch_bounds__(256) void k_gather(const unsigned* __restrict__ h,
                                                const int2* __restrict__ en,
                                                const int* __restrict__ row_ptr,
                                                const float* __restrict__ dinv,
                                                const float* __restrict__ b,
                                                float* __restrict__ out, int n) {
    int node = (int)(((long long)blockIdx.x * 256 + threadIdx.x) >> 6);
    int lane = threadIdx.x & 63;
    if (node >= n) return;
    int slot = lane >> 5, j = lane & 31;
    float di = dinv[node];
    float2 acc = make_float2(0.0f, 0.0f);
    if (slot == 0) {
        unsigned u = h[node * 32 + j];
        acc.x = b[2 * j]     + bf_lo(u) * di * di;
        acc.y = b[2 * j + 1] + bf_hi(u) * di * di;
    }
    int e0 = row_ptr[node], cnt = row_ptr[node + 1] - e0;
    int p = slot;
    for (; p + 6 < cnt; p += 8) {
        int2 a0 = en[e0 + p];
        int2 a1 = en[e0 + p + 2];
        int2 a2 = en[e0 + p + 4];
        int2 a3 = en[e0 + p + 6];
        unsigned u0 = h[a0.x * 32 + j];
        unsigned u1 = h[a1.x * 32 + j];
        unsigned u2 = h[a2.x * 32 + j];
        unsigned u3 = h[a3.x * 32 + j];
        float n0 = __int_as_float(a0.y), n1 = __int_as_float(a1.y);
        float n2 = __int_as_float(a2.y), n3 = __int_as_float(a3.y);
        acc.x = fmaf(bf_lo(u0), n0, acc.x);  acc.y = fmaf(bf_hi(u0), n0, acc.y);
        acc.x = fmaf(bf_lo(u1), n1, acc.x);  acc.y = fmaf(bf_hi(u1), n1, acc.y);
        acc.x = fmaf(bf_lo(u2), n2, acc.x);  acc.y = fmaf(bf_hi(u2), n2, acc.y);
        acc.x = fmaf(bf_lo(u3), n3, acc.x);  acc.y = fmaf(bf_hi(u3), n3, acc.y);
    }
    for (; p < cnt; p += 2) {
        int2 a0 = en[e0 + p];
        unsigned u0 = h[a0.x * 32 + j];
        float n0 = __int_as_float(a0.y);
        acc.x = fmaf(bf_lo(u0), n0, acc.x);
        acc.y = fmaf(bf_hi(u0), n0, acc.y);
    }
    acc.x += __shfl_xor(acc.x, 32);
    acc.y += __shfl_xor(acc.y, 32);
    if (slot == 0) *(float2*)&out[(long long)node * 64 + 2 * j] = acc;
}

// ---------- layer-2 transform: t = relu(agg1) @ W2, bf16 output ----------
__global__ __launch_bounds__(256) void k_trans2(const float* __restrict__ agg,
                                                const float* __restrict__ W2,
                                                unsigned short* __restrict__ t, int n,
                                                int nwaves) {
    int wid = blockIdx.x * 4 + (threadIdx.x >> 6);
    int lane = threadIdx.x & 63;
    float wcol[64];
#pragma unroll
    for (int k = 0; k < 64; ++k)
        wcol[k] = (lane < 40) ? W2[k * 40 + lane] : 0.0f;
    for (int node = wid; node < n; node += nwaves) {
        int node_u = __builtin_amdgcn_readfirstlane(node);
        const float* arow = agg + (size_t)node_u * 64;
        float acc = 0.0f;
#pragma unroll
        for (int k4 = 0; k4 < 16; ++k4) {
            float4 a = *(const float4*)(arow + k4 * 4);   // wave-uniform -> s_load
            acc = fmaf(fmaxf(a.x, 0.0f), wcol[k4 * 4 + 0], acc);
            acc = fmaf(fmaxf(a.y, 0.0f), wcol[k4 * 4 + 1], acc);
            acc = fmaf(fmaxf(a.z, 0.0f), wcol[k4 * 4 + 2], acc);
            acc = fmaf(fmaxf(a.w, 0.0f), wcol[k4 * 4 + 3], acc);
        }
        if (lane < 40) t[(size_t)node_u * 40 + lane] = f2bf(acc);
    }
}

// ---------- layer-2 gather (bf16, 2 slots x 4-edge unroll) + bias + log_softmax ----------
__global__ __launch_bounds__(256) void k_gather40(const unsigned* __restrict__ t,
                                                  const int2* __restrict__ en,
                                                  const int* __restrict__ row_ptr,
                                                  const float* __restrict__ dinv,
                                                  const float* __restrict__ b2,
                                                  float* __restrict__ out, int n) {
    int node = (int)(((long long)blockIdx.x * 256 + threadIdx.x) >> 6);
    int lane = threadIdx.x & 63;
    if (node >= n) return;
    int slot = lane >> 5, j = lane & 31;
    bool act = j < 20;
    float di = dinv[node];
    float2 acc = make_float2(0.0f, 0.0f);
    if (slot == 0 && act) {
        unsigned u = t[node * 20 + j];
        acc.x = b2[2 * j]     + bf_lo(u) * di * di;
        acc.y = b2[2 * j + 1] + bf_hi(u) * di * di;
    }
    int e0 = row_ptr[node], cnt = row_ptr[node + 1] - e0;
    int p = slot;
    for (; p + 6 < cnt; p += 8) {
        int2 a0 = en[e0 + p];
        int2 a1 = en[e0 + p + 2];
        int2 a2 = en[e0 + p + 4];
        int2 a3 = en[e0 + p + 6];
        if (act) {
            unsigned u0 = t[a0.x * 20 + j];
            unsigned u1 = t[a1.x * 20 + j];
            unsigned u2 = t[a2.x * 20 + j];
            unsigned u3 = t[a3.x * 20 + j];
            float n0 = __int_as_float(a0.y), n1 = __int_as_float(a1.y);
            float n2 = __int_as_float(a2.y), n3 = __int_as_float(a3.y);
            acc.x = fmaf(bf_lo(u0), n0, acc.x);  acc.y = fmaf(bf_hi(u0), n0, acc.y);
            acc.x = fmaf(bf_lo(u1), n1, acc.x);  acc.y = fmaf(bf_hi(u1), n1, acc.y);
            acc.x = fmaf(bf_lo(u2), n2, acc.x);  acc.y = fmaf(bf_hi(u2), n2, acc.y);
            acc.x = fmaf(bf_lo(u3), n3, acc.x);  acc.y = fmaf(bf_hi(u3), n3, acc.y);
        }
    }
    for (; p < cnt; p += 2) {
        int2 a0 = en[e0 + p];
        if (act) {
            unsigned u0 = t[a0.x * 20 + j];
            float n0 = __int_as_float(a0.y);
            acc.x = fmaf(bf_lo(u0), n0, acc.x);
            acc.y = fmaf(bf_hi(u0), n0, acc.y);
        }
    }
    acc.x += __shfl_xor(acc.x, 32);
    acc.y += __shfl_xor(acc.y, 32);
    float m = act ? fmaxf(acc.x, acc.y) : -INFINITY;
    for (int o = 32; o; o >>= 1) m = fmaxf(m, __shfl_xor(m, o));
    float ex = (act && slot == 0) ? (expf(acc.x - m) + expf(acc.y - m)) : 0.0f;
    float s = ex;
    for (int o = 32; o; o >>= 1) s += __shfl_xor(s, o);
    float ls = logf(s);
    if (slot == 0 && act) {
        float2 r = make_float2(acc.x - m - ls, acc.y - m - ls);
        *(float2*)&out[(long long)node * 40 + 2 * j] = r;
    }
}

extern "C" void kernel_launch(void* const* d_in, const int* in_sizes, int n_in,
                              void* d_out, int out_size, void* d_ws, size_t ws_size,
                              hipStream_t stream) {
    const float* x  = (const float*)d_in[0];
    const int*   ei = (const int*)d_in[1];
    const float* W1 = (const float*)d_in[2];
    const float* b1 = (const float*)d_in[3];
    const float* W2 = (const float*)d_in[4];
    const float* b2 = (const float*)d_in[5];

    const int N = in_sizes[0] / F1;      // 100000
    const int E = in_sizes[1] / 2;       // 1600000
    const int* src = ei;
    const int* dst = ei + E;

    int bsh = 8;
    while ((((N - 1) >> bsh) + 1) > NB) ++bsh;
    const int NBu = ((N - 1) >> bsh) + 1;

    // workspace layout; en aliases pairs (pairs dead after k_bfinal)
    unsigned long long* pairs = (unsigned long long*)d_ws;        // E (8 B)
    int2*  en      = (int2*)pairs;                                // E (8 B) — reuse
    float* bufB    = (float*)(pairs + E);                         // N*64 fp32 (agg1)
    unsigned* h1b  = (unsigned*)(bufB + (size_t)N * F1);          // N*32 u32 (bf16 h1)
    unsigned* tb   = h1b + (size_t)N * 32;                        // N*20 u32 (bf16 t)
    int*   srcs    = (int*)(tb + (size_t)N * 20);                 // E
    int*   row_ptr = srcs + E;                                    // N+1
    float* dinv    = (float*)(row_ptr + N + 1);                   // N
    int*   bcnt    = (int*)(dinv + N);                            // NB
    int*   bptr    = bcnt + NB;                                   // NB+1
    int*   gcur    = bptr + NB + 1;                               // NB
    float* outp    = (float*)d_out;                               // N*40

    const int B = 256;
    const int GT = (E + TILE - 1) / TILE;

    // --- CSR build (bucketed) ---
    k_zero_int<<<(NB + B - 1) / B, B, 0, stream>>>(bcnt, NB);
    k_bhist<<<GT, B, 0, stream>>>(dst, bcnt, E, bsh);
    k_bscan<<<1, NB, 0, stream>>>(bcnt, bptr, gcur, row_ptr, N, E);
    k_bscatter<<<GT, B, 0, stream>>>(src, dst, gcur, pairs, E, bsh);
    k_bfinal<<<NBu, B, 0, stream>>>(pairs, bptr, srcs, row_ptr, dinv, N, bsh);
    k_en<<<(N + 3) / 4, B, 0, stream>>>(srcs, row_ptr, dinv, en, N);   // overwrites pairs

    // --- layer 1 ---
    k_gemm1<<<(N + 3) / 4, B, 0, stream>>>(x, W1, (unsigned short*)h1b, N);
    k_gather<<<(N + 3) / 4, B, 0, stream>>>(h1b, en, row_ptr, dinv, b1, bufB, N);

    // --- layer 2 ---
    const int TB = 2048;
    k_trans2<<<TB, B, 0, stream>>>(bufB, W2, (unsigned short*)tb, N, TB * 4);
    k_gather40<<<(N + 3) / 4, B, 0, stream>>>(tb, en, row_ptr, dinv, b2, outp, N);
}

// Round 9
// 353.830 us; speedup vs baseline: 1.5803x; 1.0163x over previous
//
#include <hip/hip_runtime.h>
#include <math.h>

#define F1 64   // input/hidden features
#define F2 40   // classes
#define NB 512      // buckets for CSR build
#define TILE 4096   // edges per k_bscatter/k_bhist block (256 thr x 16)
#define CAP 9600    // max staged edges/bucket in k_enfinal (63.7 KB LDS); uniform-random
                    // dst gives ~4100±64 per bucket -> 80-sigma headroom

// ---------- bf16 helpers ----------
__device__ inline unsigned short f2bf(float f) {
    unsigned u = __float_as_uint(f);
    unsigned r = (u + 0x7FFFu + ((u >> 16) & 1u)) >> 16;   // RNE
    return (unsigned short)r;
}
__device__ inline float bf_lo(unsigned u) { return __uint_as_float(u << 16); }
__device__ inline float bf_hi(unsigned u) { return __uint_as_float(u & 0xFFFF0000u); }

// ---------- utility ----------
__global__ void k_zero_int(int* p, int n) {
    int i = blockIdx.x * blockDim.x + threadIdx.x;
    if (i < n) p[i] = 0;
}

// ---------- pass 1a: bucket histogram ----------
__global__ __launch_bounds__(256) void k_bhist(const int* __restrict__ dst,
                                               int* __restrict__ bcnt, int e, int bsh) {
    __shared__ int h[NB];
    int tid = threadIdx.x;
    for (int i = tid; i < NB; i += 256) h[i] = 0;
    __syncthreads();
    int base = blockIdx.x * TILE;
    int lim = min(base + TILE, e);
    for (int i = base + tid; i < lim; i += 256) atomicAdd(&h[dst[i] >> bsh], 1);
    __syncthreads();
    for (int i = tid; i < NB; i += 256) if (h[i]) atomicAdd(&bcnt[i], h[i]);
}

// ---------- pass 1b: scan of bucket counts ----------
__global__ __launch_bounds__(NB) void k_bscan(const int* __restrict__ bcnt,
                                              int* __restrict__ bptr, int* __restrict__ gcur,
                                              int* __restrict__ row_ptr, int n, int e) {
    __shared__ int sh[NB];
    int t = threadIdx.x;
    sh[t] = bcnt[t];
    __syncthreads();
    for (int off = 1; off < NB; off <<= 1) {
        int v = (t >= off) ? sh[t - off] : 0;
        __syncthreads();
        sh[t] += v;
        __syncthreads();
    }
    int ex = t ? sh[t - 1] : 0;
    bptr[t] = ex;
    gcur[t] = ex;
    if (t == NB - 1) bptr[NB] = sh[NB - 1];
    if (t == 0) row_ptr[n] = e;
}

// ---------- pass 1c: bucket (src,dst) pairs ----------
__global__ __launch_bounds__(256) void k_bscatter(const int* __restrict__ src,
                                                  const int* __restrict__ dst,
                                                  int* gcur,
                                                  unsigned long long* __restrict__ pairs,
                                                  int e, int bsh) {
    __shared__ int lhist[NB];
    __shared__ int lstart[NB];
    __shared__ int delta[NB];
    __shared__ unsigned long long stage[TILE];
    int tid = threadIdx.x;
    for (int i = tid; i < NB; i += 256) lhist[i] = 0;
    __syncthreads();
    int base = blockIdx.x * TILE;
    int cnt = min(TILE, e - base);
    int sA[16], dA[16], rA[16];
#pragma unroll
    for (int k = 0; k < 16; ++k) {
        int i = base + k * 256 + tid;
        if (i < e) {
            sA[k] = src[i];
            dA[k] = dst[i];
            rA[k] = atomicAdd(&lhist[dA[k] >> bsh], 1);
        }
    }
    __syncthreads();
    if (tid < 64) {
        int v[8];
        int b0 = tid * 8, s = 0;
#pragma unroll
        for (int j = 0; j < 8; ++j) { v[j] = lhist[b0 + j]; s += v[j]; }
        int sc = s;
        for (int o = 1; o < 64; o <<= 1) { int u = __shfl_up(sc, o); if (tid >= o) sc += u; }
        int ex = sc - s;
#pragma unroll
        for (int j = 0; j < 8; ++j) { lstart[b0 + j] = ex; ex += v[j]; }
    }
    __syncthreads();
    for (int i = tid; i < NB; i += 256) {
        int c = lhist[i];
        if (c) delta[i] = atomicAdd(&gcur[i], c) - lstart[i];
    }
    __syncthreads();
#pragma unroll
    for (int k = 0; k < 16; ++k) {
        int i = base + k * 256 + tid;
        if (i < e) {
            int b = dA[k] >> bsh;
            stage[lstart[b] + rA[k]] =
                ((unsigned long long)(unsigned)sA[k] << 32) | (unsigned)dA[k];
        }
    }
    __syncthreads();
    for (int p = tid; p < cnt; p += 256) {
        unsigned long long pr = stage[p];
        int b = ((int)(unsigned)pr) >> bsh;
        pairs[delta[b] + p] = pr;
    }
}

// ---------- pass 2a: per-bucket degrees -> row_ptr, dinv ----------
__global__ __launch_bounds__(256) void k_deg(const unsigned long long* __restrict__ pairs,
                                             const int* __restrict__ bptr,
                                             int* __restrict__ row_ptr,
                                             float* __restrict__ dinv,
                                             int n, int bsh) {
    __shared__ int ldeg[NB];
    __shared__ int lrow[NB];
    int b = blockIdx.x, tid = threadIdx.x;
    int beg = bptr[b], end = bptr[b + 1];
    int cnt = end - beg;
    int node0 = b << bsh;
    int bnodes = 1 << bsh;
    for (int i = tid; i < bnodes; i += 256) ldeg[i] = 0;
    __syncthreads();
    for (int p = tid; p < cnt; p += 256) {
        int d = (int)(unsigned)pairs[beg + p];
        atomicAdd(&ldeg[d - node0], 1);
    }
    __syncthreads();
    if (tid < 64) {
        int per = bnodes >> 6;
        int b0 = tid * per, s = 0;
        for (int j = 0; j < per; ++j) s += ldeg[b0 + j];
        int sc = s;
        for (int o = 1; o < 64; o <<= 1) { int u = __shfl_up(sc, o); if (tid >= o) sc += u; }
        int ex = sc - s;
        for (int j = 0; j < per; ++j) { lrow[b0 + j] = ex; ex += ldeg[b0 + j]; }
    }
    __syncthreads();
    for (int i = tid; i < bnodes; i += 256) {
        int node = node0 + i;
        if (node < n) {
            row_ptr[node] = beg + lrow[i];
            dinv[node] = rsqrtf((float)(ldeg[i] + 1));   // +1 self loop
        }
    }
}

// ---------- pass 2b: per-bucket rank + (src,norm) emit, coalesced ----------
// en aliases pairs: safe — bucket fully staged to LDS before en writes.
__global__ __launch_bounds__(256) void k_enfinal(const unsigned long long* __restrict__ pairs,
                                                 const int* __restrict__ bptr,
                                                 const int* __restrict__ row_ptr,
                                                 const float* __restrict__ dinv,
                                                 int2* __restrict__ en,
                                                 int n, int bsh) {
    __shared__ int lrow[NB];
    __shared__ int lcur[NB];
    __shared__ float dinvl[NB];
    __shared__ int sS[CAP];
    __shared__ unsigned short sD[CAP];
    int b = blockIdx.x, tid = threadIdx.x;
    int beg = bptr[b], end = bptr[b + 1];
    int cnt = end - beg;
    int node0 = b << bsh;
    int bnodes = 1 << bsh;
    for (int i = tid; i < bnodes; i += 256) {
        lcur[i] = 0;
        int node = node0 + i;
        if (node < n) {
            lrow[i] = row_ptr[node] - beg;
            dinvl[i] = dinv[node];
        }
    }
    __syncthreads();
    if (cnt <= CAP) {
        for (int p = tid; p < cnt; p += 256) {
            unsigned long long pr = pairs[beg + p];
            int dl = ((int)(unsigned)pr) - node0;
            int s = (int)(pr >> 32);
            int r = atomicAdd(&lcur[dl], 1);
            int pos = lrow[dl] + r;
            sS[pos] = s;
            sD[pos] = (unsigned short)dl;
        }
        __syncthreads();
        for (int p = tid; p < cnt; p += 256) {
            int s = sS[p];
            float nm = dinvl[sD[p]] * dinv[s];
            en[beg + p] = make_int2(s, __float_as_int(nm));
        }
    } else {
        // fallback (unreachable for uniform-random dst at this scale)
        for (int p = tid; p < cnt; p += 256) {
            unsigned long long pr = pairs[beg + p];
            int dl = ((int)(unsigned)pr) - node0;
            int s = (int)(pr >> 32);
            int r = atomicAdd(&lcur[dl], 1);
            float nm = dinvl[dl] * dinv[s];
            en[beg + lrow[dl] + r] = make_int2(s, __float_as_int(nm));
        }
    }
}

// ---------- GEMM1: h = x @ W1, bf16 output ----------
__global__ __launch_bounds__(256) void k_gemm1(const float* __restrict__ x,
                                               const float* __restrict__ W,
                                               unsigned short* __restrict__ h, int n) {
    __shared__ float Ws[64 * 64];
    __shared__ float xs[4][64];
    int tid = threadIdx.x;
#pragma unroll
    for (int i = 0; i < 16; ++i) Ws[tid + i * 256] = W[tid + i * 256];
    int r = tid >> 6, c = tid & 63;
    int row = blockIdx.x * 4 + r;
    xs[r][c] = (row < n) ? x[row * 64 + c] : 0.0f;
    __syncthreads();
    float acc = 0.0f;
#pragma unroll
    for (int k = 0; k < 64; k += 4) {
        float4 xv = *(const float4*)&xs[r][k];
        acc = fmaf(xv.x, Ws[(k + 0) * 64 + c], acc);
        acc = fmaf(xv.y, Ws[(k + 1) * 64 + c], acc);
        acc = fmaf(xv.z, Ws[(k + 2) * 64 + c], acc);
        acc = fmaf(xv.w, Ws[(k + 3) * 64 + c], acc);
    }
    if (row < n) h[row * 64 + c] = f2bf(acc);
}

// ---------- layer-1 gather: wave/node, 2 slots x 8-edge unroll, bf16x2/lane ----------
__global__ __launch_bounds__(256) void k_gather(const unsigned* __restrict__ h,
                                                const int2* __restrict__ en,
                                                const int* __restrict__ row_ptr,
                                                const float* __restrict__ dinv,
                                                const float* __restrict__ b,
                                                float* __restrict__ out, int n) {
    int node = (int)(((long long)blockIdx.x * 256 + threadIdx.x) >> 6);
    int lane = threadIdx.x & 63;
    if (node >= n) return;
    int slot = lane >> 5, j = lane & 31;
    float di = dinv[node];
    float2 acc = make_float2(0.0f, 0.0f);
    if (slot == 0) {
        unsigned u = h[node * 32 + j];
        acc.x = b[2 * j]     + bf_lo(u) * di * di;
        acc.y = b[2 * j + 1] + bf_hi(u) * di * di;
    }
    int e0 = row_ptr[node], cnt = row_ptr[node + 1] - e0;
    int p = slot;
    for (; p + 14 < cnt; p += 16) {
        int2 a[8]; unsigned u[8];
#pragma unroll
        for (int k = 0; k < 8; ++k) a[k] = en[e0 + p + 2 * k];
#pragma unroll
        for (int k = 0; k < 8; ++k) u[k] = h[a[k].x * 32 + j];
#pragma unroll
        for (int k = 0; k < 8; ++k) {
            float nm = __int_as_float(a[k].y);
            acc.x = fmaf(bf_lo(u[k]), nm, acc.x);
            acc.y = fmaf(bf_hi(u[k]), nm, acc.y);
        }
    }
    for (; p < cnt; p += 2) {
        int2 a0 = en[e0 + p];
        unsigned u0 = h[a0.x * 32 + j];
        float nm = __int_as_float(a0.y);
        acc.x = fmaf(bf_lo(u0), nm, acc.x);
        acc.y = fmaf(bf_hi(u0), nm, acc.y);
    }
    acc.x += __shfl_xor(acc.x, 32);
    acc.y += __shfl_xor(acc.y, 32);
    if (slot == 0) *(float2*)&out[(long long)node * 64 + 2 * j] = acc;
}

// ---------- layer-2 transform: t = relu(agg1) @ W2, bf16 output ----------
__global__ __launch_bounds__(256) void k_trans2(const float* __restrict__ agg,
                                                const float* __restrict__ W2,
                                                unsigned short* __restrict__ t, int n,
                                                int nwaves) {
    int wid = blockIdx.x * 4 + (threadIdx.x >> 6);
    int lane = threadIdx.x & 63;
    float wcol[64];
#pragma unroll
    for (int k = 0; k < 64; ++k)
        wcol[k] = (lane < 40) ? W2[k * 40 + lane] : 0.0f;
    for (int node = wid; node < n; node += nwaves) {
        int node_u = __builtin_amdgcn_readfirstlane(node);
        const float* arow = agg + (size_t)node_u * 64;
        float acc = 0.0f;
#pragma unroll
        for (int k4 = 0; k4 < 16; ++k4) {
            float4 a = *(const float4*)(arow + k4 * 4);   // wave-uniform -> s_load
            acc = fmaf(fmaxf(a.x, 0.0f), wcol[k4 * 4 + 0], acc);
            acc = fmaf(fmaxf(a.y, 0.0f), wcol[k4 * 4 + 1], acc);
            acc = fmaf(fmaxf(a.z, 0.0f), wcol[k4 * 4 + 2], acc);
            acc = fmaf(fmaxf(a.w, 0.0f), wcol[k4 * 4 + 3], acc);
        }
        if (lane < 40) t[(size_t)node_u * 40 + lane] = f2bf(acc);
    }
}

// ---------- layer-2 gather: 3 slots x 20 lanes, 4-edge unroll + log_softmax ----------
__global__ __launch_bounds__(256) void k_gather40(const unsigned* __restrict__ t,
                                                  const int2* __restrict__ en,
                                                  const int* __restrict__ row_ptr,
                                                  const float* __restrict__ dinv,
                                                  const float* __restrict__ b2,
                                                  float* __restrict__ out, int n) {
    int node = (int)(((long long)blockIdx.x * 256 + threadIdx.x) >> 6);
    int lane = threadIdx.x & 63;
    if (node >= n) return;
    int slot = lane / 20;            // 0..2 active, 3 idle
    int j = lane - slot * 20;        // class pair 0..19
    bool act = slot < 3;
    float di = dinv[node];
    float2 acc = make_float2(0.0f, 0.0f);
    if (slot == 0) {
        unsigned u = t[node * 20 + j];
        acc.x = b2[2 * j]     + bf_lo(u) * di * di;
        acc.y = b2[2 * j + 1] + bf_hi(u) * di * di;
    }
    int e0 = row_ptr[node];
    int cnt = act ? (row_ptr[node + 1] - e0) : 0;
    int p = slot;
    for (; p + 9 < cnt; p += 12) {
        int2 a[4]; unsigned u[4];
#pragma unroll
        for (int k = 0; k < 4; ++k) a[k] = en[e0 + p + 3 * k];
#pragma unroll
        for (int k = 0; k < 4; ++k) u[k] = t[a[k].x * 20 + j];
#pragma unroll
        for (int k = 0; k < 4; ++k) {
            float nm = __int_as_float(a[k].y);
            acc.x = fmaf(bf_lo(u[k]), nm, acc.x);
            acc.y = fmaf(bf_hi(u[k]), nm, acc.y);
        }
    }
    for (; p < cnt; p += 3) {
        int2 a0 = en[e0 + p];
        unsigned u0 = t[a0.x * 20 + j];
        float nm = __int_as_float(a0.y);
        acc.x = fmaf(bf_lo(u0), nm, acc.x);
        acc.y = fmaf(bf_hi(u0), nm, acc.y);
    }
    // combine the 3 slots: lane c (<20) needs lanes c, c+20, c+40
    float ax = acc.x + __shfl(acc.x, lane + 20) + __shfl(acc.x, lane + 40);
    float ay = acc.y + __shfl(acc.y, lane + 20) + __shfl(acc.y, lane + 40);
    bool actc = lane < 20;
    float mv = actc ? fmaxf(ax, ay) : -INFINITY;
    for (int o = 32; o; o >>= 1) mv = fmaxf(mv, __shfl_xor(mv, o));
    float ex = actc ? (expf(ax - mv) + expf(ay - mv)) : 0.0f;
    float s = ex;
    for (int o = 32; o; o >>= 1) s += __shfl_xor(s, o);
    float ls = logf(s);
    if (actc) {
        float2 r = make_float2(ax - mv - ls, ay - mv - ls);
        *(float2*)&out[(long long)node * 40 + 2 * lane] = r;
    }
}

extern "C" void kernel_launch(void* const* d_in, const int* in_sizes, int n_in,
                              void* d_out, int out_size, void* d_ws, size_t ws_size,
                              hipStream_t stream) {
    const float* x  = (const float*)d_in[0];
    const int*   ei = (const int*)d_in[1];
    const float* W1 = (const float*)d_in[2];
    const float* b1 = (const float*)d_in[3];
    const float* W2 = (const float*)d_in[4];
    const float* b2 = (const float*)d_in[5];

    const int N = in_sizes[0] / F1;      // 100000
    const int E = in_sizes[1] / 2;       // 1600000
    const int* src = ei;
    const int* dst = ei + E;

    int bsh = 8;
    while ((((N - 1) >> bsh) + 1) > NB) ++bsh;
    const int NBu = ((N - 1) >> bsh) + 1;

    // workspace layout; en aliases pairs (per-bucket staged rewrite is race-free)
    unsigned long long* pairs = (unsigned long long*)d_ws;        // E (8 B)
    int2*  en      = (int2*)pairs;                                // E (8 B) — alias
    float* bufB    = (float*)(pairs + E);                         // N*64 fp32 (agg1)
    unsigned* h1b  = (unsigned*)(bufB + (size_t)N * F1);          // N*32 u32 (bf16 h1)
    unsigned* tb   = h1b + (size_t)N * 32;                        // N*20 u32 (bf16 t)
    int*   row_ptr = (int*)(tb + (size_t)N * 20);                 // N+1
    float* dinv    = (float*)(row_ptr + N + 1);                   // N
    int*   bcnt    = (int*)(dinv + N);                            // NB
    int*   bptr    = bcnt + NB;                                   // NB+1
    int*   gcur    = bptr + NB + 1;                               // NB
    float* outp    = (float*)d_out;                               // N*40

    const int B = 256;
    const int GT = (E + TILE - 1) / TILE;

    // --- CSR build (bucketed; emits row_ptr, dinv, en) ---
    k_zero_int<<<(NB + B - 1) / B, B, 0, stream>>>(bcnt, NB);
    k_bhist<<<GT, B, 0, stream>>>(dst, bcnt, E, bsh);
    k_bscan<<<1, NB, 0, stream>>>(bcnt, bptr, gcur, row_ptr, N, E);
    k_bscatter<<<GT, B, 0, stream>>>(src, dst, gcur, pairs, E, bsh);
    k_deg<<<NBu, B, 0, stream>>>(pairs, bptr, row_ptr, dinv, N, bsh);
    k_enfinal<<<NBu, B, 0, stream>>>(pairs, bptr, row_ptr, dinv, en, N, bsh);

    // --- layer 1 ---
    k_gemm1<<<(N + 3) / 4, B, 0, stream>>>(x, W1, (unsigned short*)h1b, N);
    k_gather<<<(N + 3) / 4, B, 0, stream>>>(h1b, en, row_ptr, dinv, b1, bufB, N);

    // --- layer 2 ---
    const int TB = 2048;
    k_trans2<<<TB, B, 0, stream>>>(bufB, W2, (unsigned short*)tb, N, TB * 4);
    k_gather40<<<(N + 3) / 4, B, 0, stream>>>(tb, en, row_ptr, dinv, b2, outp, N);
}

// Round 10
// 309.913 us; speedup vs baseline: 1.8042x; 1.1417x over previous
//
#include <hip/hip_runtime.h>
#include <math.h>

#define F1 64   // input/hidden features
#define F2 40   // classes
#define NB 512      // buckets for CSR build
#define TILE 4096   // edges per k_bscatter/k_bhist block
#define FCAP 7000   // max staged edges/bucket in k_final (56 KB LDS); mean 4092, sigma 64

typedef unsigned int uint;

// ---------- bf16 helpers ----------
__device__ inline unsigned short f2bf(float f) {
    unsigned u = __float_as_uint(f);
    unsigned r = (u + 0x7FFFu + ((u >> 16) & 1u)) >> 16;   // RNE
    return (unsigned short)r;
}
__device__ inline uint packbf(float lo, float hi) {
    return (uint)f2bf(lo) | ((uint)f2bf(hi) << 16);
}
__device__ inline float bf_lo(uint u) { return __uint_as_float(u << 16); }
__device__ inline float bf_hi(uint u) { return __uint_as_float(u & 0xFFFF0000u); }

// ---------- utility ----------
__global__ void k_zero_int(int* p, int n) {
    int i = blockIdx.x * blockDim.x + threadIdx.x;
    if (i < n) p[i] = 0;
}

// ---------- pass 1a: bucket histogram ----------
__global__ __launch_bounds__(256) void k_bhist(const int* __restrict__ dst,
                                               int* __restrict__ bcnt, int e, int bsh) {
    __shared__ int h[NB];
    int tid = threadIdx.x;
    for (int i = tid; i < NB; i += 256) h[i] = 0;
    __syncthreads();
    int base = blockIdx.x * TILE;
    int lim = min(base + TILE, e);
    for (int i = base + tid; i < lim; i += 256) atomicAdd(&h[dst[i] >> bsh], 1);
    __syncthreads();
    for (int i = tid; i < NB; i += 256) if (h[i]) atomicAdd(&bcnt[i], h[i]);
}

// ---------- pass 1b: scan of bucket counts ----------
__global__ __launch_bounds__(NB) void k_bscan(const int* __restrict__ bcnt,
                                              int* __restrict__ bptr, int* __restrict__ gcur,
                                              int* __restrict__ row_ptr, int n, int e) {
    __shared__ int sh[NB];
    int t = threadIdx.x;
    sh[t] = bcnt[t];
    __syncthreads();
    for (int off = 1; off < NB; off <<= 1) {
        int v = (t >= off) ? sh[t - off] : 0;
        __syncthreads();
        sh[t] += v;
        __syncthreads();
    }
    int ex = t ? sh[t - 1] : 0;
    bptr[t] = ex;
    gcur[t] = ex;
    if (t == NB - 1) bptr[NB] = sh[NB - 1];
    if (t == 0) row_ptr[n] = e;
}

// ---------- pass 1c: bucket (src,dst) pairs ----------
__global__ __launch_bounds__(256) void k_bscatter(const int* __restrict__ src,
                                                  const int* __restrict__ dst,
                                                  int* gcur,
                                                  unsigned long long* __restrict__ pairs,
                                                  int e, int bsh) {
    __shared__ int lhist[NB];
    __shared__ int lstart[NB];
    __shared__ int delta[NB];
    __shared__ unsigned long long stage[TILE];
    int tid = threadIdx.x;
    for (int i = tid; i < NB; i += 256) lhist[i] = 0;
    __syncthreads();
    int base = blockIdx.x * TILE;
    int cnt = min(TILE, e - base);
    int sA[16], dA[16], rA[16];
#pragma unroll
    for (int k = 0; k < 16; ++k) {
        int i = base + k * 256 + tid;
        if (i < e) {
            sA[k] = src[i];
            dA[k] = dst[i];
            rA[k] = atomicAdd(&lhist[dA[k] >> bsh], 1);
        }
    }
    __syncthreads();
    if (tid < 64) {
        int v[8];
        int b0 = tid * 8, s = 0;
#pragma unroll
        for (int j = 0; j < 8; ++j) { v[j] = lhist[b0 + j]; s += v[j]; }
        int sc = s;
        for (int o = 1; o < 64; o <<= 1) { int u = __shfl_up(sc, o); if (tid >= o) sc += u; }
        int ex = sc - s;
#pragma unroll
        for (int j = 0; j < 8; ++j) { lstart[b0 + j] = ex; ex += v[j]; }
    }
    __syncthreads();
    for (int i = tid; i < NB; i += 256) {
        int c = lhist[i];
        if (c) delta[i] = atomicAdd(&gcur[i], c) - lstart[i];
    }
    __syncthreads();
#pragma unroll
    for (int k = 0; k < 16; ++k) {
        int i = base + k * 256 + tid;
        if (i < e) {
            int b = dA[k] >> bsh;
            stage[lstart[b] + rA[k]] =
                ((unsigned long long)(unsigned)sA[k] << 32) | (unsigned)dA[k];
        }
    }
    __syncthreads();
    for (int p = tid; p < cnt; p += 256) {
        unsigned long long pr = stage[p];
        int b = ((int)(unsigned)pr) >> bsh;
        pairs[delta[b] + p] = pr;
    }
}

// ---------- pass 2: per-bucket finalize: row_ptr, dinv, srcs (one pairs read) ----------
__global__ __launch_bounds__(256) void k_final(const unsigned long long* __restrict__ pairs,
                                               const int* __restrict__ bptr,
                                               int* __restrict__ srcs,
                                               int* __restrict__ row_ptr,
                                               float* __restrict__ dinv,
                                               int n, int bsh) {
    __shared__ int ldeg[NB];
    __shared__ int lrow[NB];
    __shared__ int lcur[NB];
    __shared__ unsigned long long stg[FCAP];
    int b = blockIdx.x, tid = threadIdx.x;
    int beg = bptr[b], cnt = bptr[b + 1] - beg;
    int node0 = b << bsh;
    int bnodes = 1 << bsh;
    for (int i = tid; i < bnodes; i += 256) { ldeg[i] = 0; lcur[i] = 0; }
    bool fit = cnt <= FCAP;
    __syncthreads();
    if (fit) {
        for (int p = tid; p < cnt; p += 256) {
            unsigned long long pr = pairs[beg + p];
            stg[p] = pr;
            atomicAdd(&ldeg[((int)(unsigned)pr) - node0], 1);
        }
    } else {
        for (int p = tid; p < cnt; p += 256)
            atomicAdd(&ldeg[((int)(unsigned)pairs[beg + p]) - node0], 1);
    }
    __syncthreads();
    if (tid < 64) {
        int per = bnodes >> 6;
        int b0 = tid * per, s = 0;
        for (int j = 0; j < per; ++j) s += ldeg[b0 + j];
        int sc = s;
        for (int o = 1; o < 64; o <<= 1) { int u = __shfl_up(sc, o); if (tid >= o) sc += u; }
        int ex = sc - s;
        for (int j = 0; j < per; ++j) { lrow[b0 + j] = ex; ex += ldeg[b0 + j]; }
    }
    __syncthreads();
    for (int i = tid; i < bnodes; i += 256) {
        int node = node0 + i;
        if (node < n) {
            row_ptr[node] = beg + lrow[i];
            dinv[node] = rsqrtf((float)(ldeg[i] + 1));   // +1 self loop
        }
    }
    if (fit) {
        for (int p = tid; p < cnt; p += 256) {
            unsigned long long pr = stg[p];
            int dl = ((int)(unsigned)pr) - node0;
            int r = atomicAdd(&lcur[dl], 1);
            srcs[beg + lrow[dl] + r] = (int)(pr >> 32);   // stores land in L2 window
        }
    } else {
        for (int p = tid; p < cnt; p += 256) {
            unsigned long long pr = pairs[beg + p];
            int dl = ((int)(unsigned)pr) - node0;
            int r = atomicAdd(&lcur[dl], 1);
            srcs[beg + lrow[dl] + r] = (int)(pr >> 32);
        }
    }
}

// ---------- GEMM1: hs = dinv[row] * (x @ W1), bf16 ----------
__global__ __launch_bounds__(256) void k_gemm1(const float* __restrict__ x,
                                               const float* __restrict__ W,
                                               const float* __restrict__ dinv,
                                               unsigned short* __restrict__ h, int n) {
    __shared__ float Ws[64 * 64];
    __shared__ float xs[4][64];
    int tid = threadIdx.x;
#pragma unroll
    for (int i = 0; i < 16; ++i) Ws[tid + i * 256] = W[tid + i * 256];
    int r = tid >> 6, c = tid & 63;
    int row = blockIdx.x * 4 + r;
    xs[r][c] = (row < n) ? x[row * 64 + c] : 0.0f;
    __syncthreads();
    float acc = 0.0f;
#pragma unroll
    for (int k = 0; k < 64; k += 4) {
        float4 xv = *(const float4*)&xs[r][k];
        acc = fmaf(xv.x, Ws[(k + 0) * 64 + c], acc);
        acc = fmaf(xv.y, Ws[(k + 1) * 64 + c], acc);
        acc = fmaf(xv.z, Ws[(k + 2) * 64 + c], acc);
        acc = fmaf(xv.w, Ws[(k + 3) * 64 + c], acc);
    }
    if (row < n) h[row * 64 + c] = f2bf(acc * dinv[row]);
}

// ---------- layer-1 gather: 8 lanes/edge x uint4, plain row sum ----------
// out per node: relu(dinv_i * (hs_i + sum hs_j) + b1) as bf16 uint4 rows.
__global__ __launch_bounds__(256) void k_gather(const uint4* __restrict__ h4,
                                                const int* __restrict__ srcs,
                                                const int* __restrict__ row_ptr,
                                                const float* __restrict__ dinv,
                                                const float* __restrict__ b,
                                                uint4* __restrict__ aggb, int n) {
    int node = __builtin_amdgcn_readfirstlane(
        (int)(((long long)blockIdx.x * 256 + threadIdx.x) >> 6));
    int lane = threadIdx.x & 63;
    if (node >= n) return;
    int slot = lane >> 3, j = lane & 7;
    float a0x=0,a0y=0,a1x=0,a1y=0,a2x=0,a2y=0,a3x=0,a3y=0;
    if (slot == 0) {
        uint4 u = h4[(size_t)node * 8 + j];
        a0x = bf_lo(u.x); a0y = bf_hi(u.x);
        a1x = bf_lo(u.y); a1y = bf_hi(u.y);
        a2x = bf_lo(u.z); a2y = bf_hi(u.z);
        a3x = bf_lo(u.w); a3y = bf_hi(u.w);
    }
    int e0 = row_ptr[node], cnt = row_ptr[node + 1] - e0;
    int p = slot;
    for (; p + 8 < cnt; p += 16) {
        int s0 = srcs[e0 + p], s1 = srcs[e0 + p + 8];
        uint4 u0 = h4[(size_t)s0 * 8 + j];
        uint4 u1 = h4[(size_t)s1 * 8 + j];
        a0x += bf_lo(u0.x) + bf_lo(u1.x);  a0y += bf_hi(u0.x) + bf_hi(u1.x);
        a1x += bf_lo(u0.y) + bf_lo(u1.y);  a1y += bf_hi(u0.y) + bf_hi(u1.y);
        a2x += bf_lo(u0.z) + bf_lo(u1.z);  a2y += bf_hi(u0.z) + bf_hi(u1.z);
        a3x += bf_lo(u0.w) + bf_lo(u1.w);  a3y += bf_hi(u0.w) + bf_hi(u1.w);
    }
    for (; p < cnt; p += 8) {
        int s0 = srcs[e0 + p];
        uint4 u0 = h4[(size_t)s0 * 8 + j];
        a0x += bf_lo(u0.x);  a0y += bf_hi(u0.x);
        a1x += bf_lo(u0.y);  a1y += bf_hi(u0.y);
        a2x += bf_lo(u0.z);  a2y += bf_hi(u0.z);
        a3x += bf_lo(u0.w);  a3y += bf_hi(u0.w);
    }
#define COMB(o) \
    a0x += __shfl_xor(a0x, o); a0y += __shfl_xor(a0y, o); \
    a1x += __shfl_xor(a1x, o); a1y += __shfl_xor(a1y, o); \
    a2x += __shfl_xor(a2x, o); a2y += __shfl_xor(a2y, o); \
    a3x += __shfl_xor(a3x, o); a3y += __shfl_xor(a3y, o);
    COMB(8) COMB(16) COMB(32)
#undef COMB
    if (slot == 0) {
        float di = dinv[node];
        float4 bl = *(const float4*)&b[8 * j];
        float4 bh = *(const float4*)&b[8 * j + 4];
        float v0 = fmaxf(fmaf(a0x, di, bl.x), 0.0f);
        float v1 = fmaxf(fmaf(a0y, di, bl.y), 0.0f);
        float v2 = fmaxf(fmaf(a1x, di, bl.z), 0.0f);
        float v3 = fmaxf(fmaf(a1y, di, bl.w), 0.0f);
        float v4 = fmaxf(fmaf(a2x, di, bh.x), 0.0f);
        float v5 = fmaxf(fmaf(a2y, di, bh.y), 0.0f);
        float v6 = fmaxf(fmaf(a3x, di, bh.z), 0.0f);
        float v7 = fmaxf(fmaf(a3y, di, bh.w), 0.0f);
        uint4 r;
        r.x = packbf(v0, v1); r.y = packbf(v2, v3);
        r.z = packbf(v4, v5); r.w = packbf(v6, v7);
        aggb[(size_t)node * 8 + j] = r;
    }
}

// ---------- layer-2 transform: ts = dinv * (agg_relu_bf16 @ W2), bf16 ----------
__global__ __launch_bounds__(256) void k_trans2(const uint* __restrict__ aggu,
                                                const float* __restrict__ W2,
                                                const float* __restrict__ dinv,
                                                unsigned short* __restrict__ t, int n,
                                                int nwaves) {
    int wid = blockIdx.x * 4 + (threadIdx.x >> 6);
    int lane = threadIdx.x & 63;
    float wcol[64];
#pragma unroll
    for (int k = 0; k < 64; ++k)
        wcol[k] = (lane < 40) ? W2[k * 40 + lane] : 0.0f;
    for (int node = wid; node < n; node += nwaves) {
        int node_u = __builtin_amdgcn_readfirstlane(node);
        const uint* arow = aggu + (size_t)node_u * 32;
        float acc = 0.0f;
#pragma unroll
        for (int k4 = 0; k4 < 8; ++k4) {
            uint4 a = *(const uint4*)(arow + k4 * 4);   // wave-uniform -> s_load
            acc = fmaf(bf_lo(a.x), wcol[8 * k4 + 0], acc);
            acc = fmaf(bf_hi(a.x), wcol[8 * k4 + 1], acc);
            acc = fmaf(bf_lo(a.y), wcol[8 * k4 + 2], acc);
            acc = fmaf(bf_hi(a.y), wcol[8 * k4 + 3], acc);
            acc = fmaf(bf_lo(a.z), wcol[8 * k4 + 4], acc);
            acc = fmaf(bf_hi(a.z), wcol[8 * k4 + 5], acc);
            acc = fmaf(bf_lo(a.w), wcol[8 * k4 + 6], acc);
            acc = fmaf(bf_hi(a.w), wcol[8 * k4 + 7], acc);
        }
        float di = dinv[node_u];
        if (lane < 40) t[(size_t)node_u * 40 + lane] = f2bf(acc * di);
    }
}

// ---------- layer-2 gather: 10 lanes/edge x uint2, 6 slots + log_softmax ----------
__global__ __launch_bounds__(256) void k_gather40(const uint2* __restrict__ t2,
                                                  const int* __restrict__ srcs,
                                                  const int* __restrict__ row_ptr,
                                                  const float* __restrict__ dinv,
                                                  const float* __restrict__ b2,
                                                  float* __restrict__ out, int n) {
    int node = __builtin_amdgcn_readfirstlane(
        (int)(((long long)blockIdx.x * 256 + threadIdx.x) >> 6));
    int lane = threadIdx.x & 63;
    if (node >= n) return;
    int slot = lane / 10;            // 0..5 active, 6 idle (lanes 60-63)
    int j = lane - slot * 10;        // uint2 index 0..9 (classes 4j..4j+3)
    bool act = slot < 6;
    float a0=0, a1=0, a2=0, a3=0;
    if (slot == 0) {
        uint2 u = t2[(size_t)node * 10 + j];
        a0 = bf_lo(u.x); a1 = bf_hi(u.x);
        a2 = bf_lo(u.y); a3 = bf_hi(u.y);
    }
    int e0 = row_ptr[node];
    int cnt = act ? (row_ptr[node + 1] - e0) : 0;
    int p = slot;
    for (; p + 6 < cnt; p += 12) {
        int s0 = srcs[e0 + p], s1 = srcs[e0 + p + 6];
        uint2 u0 = t2[(size_t)s0 * 10 + j];
        uint2 u1 = t2[(size_t)s1 * 10 + j];
        a0 += bf_lo(u0.x) + bf_lo(u1.x);  a1 += bf_hi(u0.x) + bf_hi(u1.x);
        a2 += bf_lo(u0.y) + bf_lo(u1.y);  a3 += bf_hi(u0.y) + bf_hi(u1.y);
    }
    for (; p < cnt; p += 6) {
        int s0 = srcs[e0 + p];
        uint2 u0 = t2[(size_t)s0 * 10 + j];
        a0 += bf_lo(u0.x);  a1 += bf_hi(u0.x);
        a2 += bf_lo(u0.y);  a3 += bf_hi(u0.y);
    }
    // combine the 6 slots into lanes 0..9
    float t0 = a0, t1 = a1, t2s = a2, t3 = a3;
#pragma unroll
    for (int o = 10; o <= 50; o += 10) {
        t0 += __shfl(a0, lane + o);
        t1 += __shfl(a1, lane + o);
        t2s += __shfl(a2, lane + o);
        t3 += __shfl(a3, lane + o);
    }
    bool actc = lane < 10;
    float di = dinv[node];
    float4 bb = actc ? *(const float4*)&b2[4 * lane] : make_float4(0, 0, 0, 0);
    float v0 = fmaf(t0, di, bb.x);
    float v1 = fmaf(t1, di, bb.y);
    float v2 = fmaf(t2s, di, bb.z);
    float v3 = fmaf(t3, di, bb.w);
    float mv = actc ? fmaxf(fmaxf(v0, v1), fmaxf(v2, v3)) : -INFINITY;
    for (int o = 32; o; o >>= 1) mv = fmaxf(mv, __shfl_xor(mv, o));
    float ex = actc ? (expf(v0 - mv) + expf(v1 - mv) + expf(v2 - mv) + expf(v3 - mv)) : 0.0f;
    float s = ex;
    for (int o = 32; o; o >>= 1) s += __shfl_xor(s, o);
    float ls = mv + logf(s);
    if (actc) {
        float4 r = make_float4(v0 - ls, v1 - ls, v2 - ls, v3 - ls);
        *(float4*)&out[(size_t)node * 40 + 4 * lane] = r;
    }
}

extern "C" void kernel_launch(void* const* d_in, const int* in_sizes, int n_in,
                              void* d_out, int out_size, void* d_ws, size_t ws_size,
                              hipStream_t stream) {
    const float* x  = (const float*)d_in[0];
    const int*   ei = (const int*)d_in[1];
    const float* W1 = (const float*)d_in[2];
    const float* b1 = (const float*)d_in[3];
    const float* W2 = (const float*)d_in[4];
    const float* b2 = (const float*)d_in[5];

    const int N = in_sizes[0] / F1;      // 100000
    const int E = in_sizes[1] / 2;       // 1600000
    const int* src = ei;
    const int* dst = ei + E;

    int bsh = 8;
    while ((((N - 1) >> bsh) + 1) > NB) ++bsh;
    const int NBu = ((N - 1) >> bsh) + 1;

    // workspace layout (16 B-aligned arrays first)
    uint4* h1b     = (uint4*)d_ws;                                // N*8 uint4 (bf16 hs)
    uint4* aggb    = h1b + (size_t)N * 8;                         // N*8 uint4 (relu agg bf16)
    uint2* tb      = (uint2*)(aggb + (size_t)N * 8);              // N*10 uint2 (bf16 ts)
    unsigned long long* pairs = (unsigned long long*)(tb + (size_t)N * 10);  // E
    int*   srcs    = (int*)(pairs + E);                           // E
    int*   row_ptr = srcs + E;                                    // N+1
    float* dinv    = (float*)(row_ptr + N + 1);                   // N
    int*   bcnt    = (int*)(dinv + N);                            // NB
    int*   bptr    = bcnt + NB;                                   // NB+1
    int*   gcur    = bptr + NB + 1;                               // NB
    float* outp    = (float*)d_out;                               // N*40

    const int B = 256;
    const int GT = (E + TILE - 1) / TILE;

    // --- CSR build (bucketed; emits row_ptr, dinv, srcs) ---
    k_zero_int<<<(NB + B - 1) / B, B, 0, stream>>>(bcnt, NB);
    k_bhist<<<GT, B, 0, stream>>>(dst, bcnt, E, bsh);
    k_bscan<<<1, NB, 0, stream>>>(bcnt, bptr, gcur, row_ptr, N, E);
    k_bscatter<<<GT, B, 0, stream>>>(src, dst, gcur, pairs, E, bsh);
    k_final<<<NBu, B, 0, stream>>>(pairs, bptr, srcs, row_ptr, dinv, N, bsh);

    // --- layer 1: scaled GEMM (bf16) then plain-sum gather -> relu bf16 ---
    k_gemm1<<<(N + 3) / 4, B, 0, stream>>>(x, W1, dinv, (unsigned short*)h1b, N);
    k_gather<<<(N + 3) / 4, B, 0, stream>>>(h1b, srcs, row_ptr, dinv, b1, aggb, N);

    // --- layer 2: scaled transform (bf16), plain-sum gather + bias + log_softmax ---
    const int TB = 2048;
    k_trans2<<<TB, B, 0, stream>>>((const uint*)aggb, W2, dinv, (unsigned short*)tb, N, TB * 4);
    k_gather40<<<(N + 3) / 4, B, 0, stream>>>(tb, srcs, row_ptr, dinv, b2, outp, N);
}

// Round 11
// 295.952 us; speedup vs baseline: 1.8893x; 1.0472x over previous
//
#include <hip/hip_runtime.h>
#include <math.h>

#define F1 64   // input/hidden features
#define F2 40   // classes
#define NB 1024     // buckets for CSR build (bsh=7 -> 128 nodes/bucket)
#define TILE 4096   // edges per k_bscatter/k_bhist block
#define FCAP 3200   // max staged edges/bucket in k_final (25.6 KB); mean 2046, sigma 45

typedef unsigned int uint;

// ---------- bf16 helpers ----------
__device__ inline unsigned short f2bf(float f) {
    unsigned u = __float_as_uint(f);
    unsigned r = (u + 0x7FFFu + ((u >> 16) & 1u)) >> 16;   // RNE
    return (unsigned short)r;
}
__device__ inline uint packbf(float lo, float hi) {
    return (uint)f2bf(lo) | ((uint)f2bf(hi) << 16);
}
__device__ inline float bf_lo(uint u) { return __uint_as_float(u << 16); }
__device__ inline float bf_hi(uint u) { return __uint_as_float(u & 0xFFFF0000u); }

// ---------- pass 1a: bucket histogram ----------
__global__ __launch_bounds__(256) void k_bhist(const int* __restrict__ dst,
                                               int* __restrict__ bcnt, int e, int bsh) {
    __shared__ int h[NB];
    int tid = threadIdx.x;
    for (int i = tid; i < NB; i += 256) h[i] = 0;
    __syncthreads();
    int base = blockIdx.x * TILE;
    int lim = min(base + TILE, e);
    for (int i = base + tid; i < lim; i += 256) atomicAdd(&h[dst[i] >> bsh], 1);
    __syncthreads();
    for (int i = tid; i < NB; i += 256) if (h[i]) atomicAdd(&bcnt[i], h[i]);
}

// ---------- pass 1b: scan of bucket counts ----------
__global__ __launch_bounds__(NB) void k_bscan(const int* __restrict__ bcnt,
                                              int* __restrict__ bptr, int* __restrict__ gcur,
                                              int* __restrict__ row_ptr, int n, int e) {
    __shared__ int sh[NB];
    int t = threadIdx.x;
    sh[t] = bcnt[t];
    __syncthreads();
    for (int off = 1; off < NB; off <<= 1) {
        int v = (t >= off) ? sh[t - off] : 0;
        __syncthreads();
        sh[t] += v;
        __syncthreads();
    }
    int ex = t ? sh[t - 1] : 0;
    bptr[t] = ex;
    gcur[t] = ex;
    if (t == NB - 1) bptr[NB] = sh[NB - 1];
    if (t == 0) row_ptr[n] = e;
}

// ---------- pass 1c: bucket (src,dst) pairs ----------
__global__ __launch_bounds__(256) void k_bscatter(const int* __restrict__ src,
                                                  const int* __restrict__ dst,
                                                  int* gcur,
                                                  unsigned long long* __restrict__ pairs,
                                                  int e, int bsh) {
    __shared__ int lhist[NB];
    __shared__ int lstart[NB];
    __shared__ int delta[NB];
    __shared__ unsigned long long stage[TILE];
    int tid = threadIdx.x;
    for (int i = tid; i < NB; i += 256) lhist[i] = 0;
    __syncthreads();
    int base = blockIdx.x * TILE;
    int cnt = min(TILE, e - base);
    int sA[16], dA[16], rA[16];
#pragma unroll
    for (int k = 0; k < 16; ++k) {
        int i = base + k * 256 + tid;
        if (i < e) {
            sA[k] = src[i];
            dA[k] = dst[i];
            rA[k] = atomicAdd(&lhist[dA[k] >> bsh], 1);
        }
    }
    __syncthreads();
    if (tid < 64) {
        const int per = NB / 64;
        int v[per];
        int b0 = tid * per, s = 0;
#pragma unroll
        for (int j = 0; j < per; ++j) { v[j] = lhist[b0 + j]; s += v[j]; }
        int sc = s;
        for (int o = 1; o < 64; o <<= 1) { int u = __shfl_up(sc, o); if (tid >= o) sc += u; }
        int ex = sc - s;
#pragma unroll
        for (int j = 0; j < per; ++j) { lstart[b0 + j] = ex; ex += v[j]; }
    }
    __syncthreads();
    for (int i = tid; i < NB; i += 256) {
        int c = lhist[i];
        if (c) delta[i] = atomicAdd(&gcur[i], c) - lstart[i];
    }
    __syncthreads();
#pragma unroll
    for (int k = 0; k < 16; ++k) {
        int i = base + k * 256 + tid;
        if (i < e) {
            int b = dA[k] >> bsh;
            stage[lstart[b] + rA[k]] =
                ((unsigned long long)(unsigned)sA[k] << 32) | (unsigned)dA[k];
        }
    }
    __syncthreads();
    for (int p = tid; p < cnt; p += 256) {
        unsigned long long pr = stage[p];
        int b = ((int)(unsigned)pr) >> bsh;
        pairs[delta[b] + p] = pr;
    }
}

// ---------- pass 2: per-bucket finalize: row_ptr, dinv, srcs ----------
__global__ __launch_bounds__(256) void k_final(const unsigned long long* __restrict__ pairs,
                                               const int* __restrict__ bptr,
                                               int* __restrict__ srcs,
                                               int* __restrict__ row_ptr,
                                               float* __restrict__ dinv,
                                               int n, int bsh) {
    __shared__ int ldeg[128];
    __shared__ int lrow[128];
    __shared__ int lcur[128];
    __shared__ unsigned long long stg[FCAP];
    int b = blockIdx.x, tid = threadIdx.x;
    int beg = bptr[b], cnt = bptr[b + 1] - beg;
    int node0 = b << bsh;
    int bnodes = 1 << bsh;   // 128
    for (int i = tid; i < bnodes; i += 256) { ldeg[i] = 0; lcur[i] = 0; }
    bool fit = cnt <= FCAP;
    __syncthreads();
    if (fit) {
        for (int p = tid; p < cnt; p += 256) {
            unsigned long long pr = pairs[beg + p];
            stg[p] = pr;
            atomicAdd(&ldeg[((int)(unsigned)pr) - node0], 1);
        }
    } else {
        for (int p = tid; p < cnt; p += 256)
            atomicAdd(&ldeg[((int)(unsigned)pairs[beg + p]) - node0], 1);
    }
    __syncthreads();
    if (tid < 64) {
        int per = bnodes >> 6;   // 2
        int b0 = tid * per, s = 0;
        for (int j = 0; j < per; ++j) s += ldeg[b0 + j];
        int sc = s;
        for (int o = 1; o < 64; o <<= 1) { int u = __shfl_up(sc, o); if (tid >= o) sc += u; }
        int ex = sc - s;
        for (int j = 0; j < per; ++j) { lrow[b0 + j] = ex; ex += ldeg[b0 + j]; }
    }
    __syncthreads();
    for (int i = tid; i < bnodes; i += 256) {
        int node = node0 + i;
        if (node < n) {
            row_ptr[node] = beg + lrow[i];
            dinv[node] = rsqrtf((float)(ldeg[i] + 1));   // +1 self loop
        }
    }
    if (fit) {
        for (int p = tid; p < cnt; p += 256) {
            unsigned long long pr = stg[p];
            int dl = ((int)(unsigned)pr) - node0;
            int r = atomicAdd(&lcur[dl], 1);
            srcs[beg + lrow[dl] + r] = (int)(pr >> 32);
        }
    } else {
        for (int p = tid; p < cnt; p += 256) {
            unsigned long long pr = pairs[beg + p];
            int dl = ((int)(unsigned)pr) - node0;
            int r = atomicAdd(&lcur[dl], 1);
            srcs[beg + lrow[dl] + r] = (int)(pr >> 32);
        }
    }
}

// ---------- GEMM1: hs = dinv[row] * (x @ W1), bf16 ----------
__global__ __launch_bounds__(256) void k_gemm1(const float* __restrict__ x,
                                               const float* __restrict__ W,
                                               const float* __restrict__ dinv,
                                               unsigned short* __restrict__ h, int n) {
    __shared__ float Ws[64 * 64];
    __shared__ float xs[4][64];
    int tid = threadIdx.x;
#pragma unroll
    for (int i = 0; i < 16; ++i) Ws[tid + i * 256] = W[tid + i * 256];
    int r = tid >> 6, c = tid & 63;
    int row = blockIdx.x * 4 + r;
    xs[r][c] = (row < n) ? x[row * 64 + c] : 0.0f;
    __syncthreads();
    float acc = 0.0f;
#pragma unroll
    for (int k = 0; k < 64; k += 4) {
        float4 xv = *(const float4*)&xs[r][k];
        acc = fmaf(xv.x, Ws[(k + 0) * 64 + c], acc);
        acc = fmaf(xv.y, Ws[(k + 1) * 64 + c], acc);
        acc = fmaf(xv.z, Ws[(k + 2) * 64 + c], acc);
        acc = fmaf(xv.w, Ws[(k + 3) * 64 + c], acc);
    }
    if (row < n) h[row * 64 + c] = f2bf(acc * dinv[row]);
}

// ---------- layer-1 gather: one node per HALF-wave, 4 slots x 8 lanes x uint4 ----------
__global__ __launch_bounds__(256) void k_gather(const uint4* __restrict__ h4,
                                                const int* __restrict__ srcs,
                                                const int* __restrict__ row_ptr,
                                                const float* __restrict__ dinv,
                                                const float* __restrict__ b,
                                                uint4* __restrict__ aggb, int n) {
    int node = (int)(((long long)blockIdx.x * 256 + threadIdx.x) >> 5);
    int l32 = threadIdx.x & 31;
    if (node >= n) return;
    int slot = l32 >> 3, j = l32 & 7;
    float a0x=0,a0y=0,a1x=0,a1y=0,a2x=0,a2y=0,a3x=0,a3y=0;
    if (slot == 0) {
        uint4 u = h4[(size_t)node * 8 + j];
        a0x = bf_lo(u.x); a0y = bf_hi(u.x);
        a1x = bf_lo(u.y); a1y = bf_hi(u.y);
        a2x = bf_lo(u.z); a2y = bf_hi(u.z);
        a3x = bf_lo(u.w); a3y = bf_hi(u.w);
    }
    int e0 = row_ptr[node], cnt = row_ptr[node + 1] - e0;
    int p = slot;
    for (; p + 4 < cnt; p += 8) {
        int s0 = srcs[e0 + p], s1 = srcs[e0 + p + 4];
        uint4 u0 = h4[(size_t)s0 * 8 + j];
        uint4 u1 = h4[(size_t)s1 * 8 + j];
        a0x += bf_lo(u0.x) + bf_lo(u1.x);  a0y += bf_hi(u0.x) + bf_hi(u1.x);
        a1x += bf_lo(u0.y) + bf_lo(u1.y);  a1y += bf_hi(u0.y) + bf_hi(u1.y);
        a2x += bf_lo(u0.z) + bf_lo(u1.z);  a2y += bf_hi(u0.z) + bf_hi(u1.z);
        a3x += bf_lo(u0.w) + bf_lo(u1.w);  a3y += bf_hi(u0.w) + bf_hi(u1.w);
    }
    for (; p < cnt; p += 4) {
        int s0 = srcs[e0 + p];
        uint4 u0 = h4[(size_t)s0 * 8 + j];
        a0x += bf_lo(u0.x);  a0y += bf_hi(u0.x);
        a1x += bf_lo(u0.y);  a1y += bf_hi(u0.y);
        a2x += bf_lo(u0.z);  a2y += bf_hi(u0.z);
        a3x += bf_lo(u0.w);  a3y += bf_hi(u0.w);
    }
    // combine slots within the 32-lane half (xor masks < 32 stay in-half)
#define COMB(o) \
    a0x += __shfl_xor(a0x, o); a0y += __shfl_xor(a0y, o); \
    a1x += __shfl_xor(a1x, o); a1y += __shfl_xor(a1y, o); \
    a2x += __shfl_xor(a2x, o); a2y += __shfl_xor(a2y, o); \
    a3x += __shfl_xor(a3x, o); a3y += __shfl_xor(a3y, o);
    COMB(8) COMB(16)
#undef COMB
    if (slot == 0) {
        float di = dinv[node];
        float4 bl = *(const float4*)&b[8 * j];
        float4 bh = *(const float4*)&b[8 * j + 4];
        float v0 = fmaxf(fmaf(a0x, di, bl.x), 0.0f);
        float v1 = fmaxf(fmaf(a0y, di, bl.y), 0.0f);
        float v2 = fmaxf(fmaf(a1x, di, bl.z), 0.0f);
        float v3 = fmaxf(fmaf(a1y, di, bl.w), 0.0f);
        float v4 = fmaxf(fmaf(a2x, di, bh.x), 0.0f);
        float v5 = fmaxf(fmaf(a2y, di, bh.y), 0.0f);
        float v6 = fmaxf(fmaf(a3x, di, bh.z), 0.0f);
        float v7 = fmaxf(fmaf(a3y, di, bh.w), 0.0f);
        uint4 r;
        r.x = packbf(v0, v1); r.y = packbf(v2, v3);
        r.z = packbf(v4, v5); r.w = packbf(v6, v7);
        aggb[(size_t)node * 8 + j] = r;
    }
}

// ---------- layer-2 transform: ts = dinv * (agg_relu_bf16 @ W2), bf16 ----------
__global__ __launch_bounds__(256) void k_trans2(const uint* __restrict__ aggu,
                                                const float* __restrict__ W2,
                                                const float* __restrict__ dinv,
                                                unsigned short* __restrict__ t, int n,
                                                int nwaves) {
    int wid = blockIdx.x * 4 + (threadIdx.x >> 6);
    int lane = threadIdx.x & 63;
    float wcol[64];
#pragma unroll
    for (int k = 0; k < 64; ++k)
        wcol[k] = (lane < 40) ? W2[k * 40 + lane] : 0.0f;
    for (int node = wid; node < n; node += nwaves) {
        int node_u = __builtin_amdgcn_readfirstlane(node);
        const uint* arow = aggu + (size_t)node_u * 32;
        float acc = 0.0f;
#pragma unroll
        for (int k4 = 0; k4 < 8; ++k4) {
            uint4 a = *(const uint4*)(arow + k4 * 4);   // wave-uniform -> s_load
            acc = fmaf(bf_lo(a.x), wcol[8 * k4 + 0], acc);
            acc = fmaf(bf_hi(a.x), wcol[8 * k4 + 1], acc);
            acc = fmaf(bf_lo(a.y), wcol[8 * k4 + 2], acc);
            acc = fmaf(bf_hi(a.y), wcol[8 * k4 + 3], acc);
            acc = fmaf(bf_lo(a.z), wcol[8 * k4 + 4], acc);
            acc = fmaf(bf_hi(a.z), wcol[8 * k4 + 5], acc);
            acc = fmaf(bf_lo(a.w), wcol[8 * k4 + 6], acc);
            acc = fmaf(bf_hi(a.w), wcol[8 * k4 + 7], acc);
        }
        float di = dinv[node_u];
        if (lane < 40) t[(size_t)node_u * 40 + lane] = f2bf(acc * di);
    }
}

// ---------- layer-2 gather: one node per HALF-wave, 3 slots x 10 lanes x uint2 ----------
__global__ __launch_bounds__(256) void k_gather40(const uint2* __restrict__ t2,
                                                  const int* __restrict__ srcs,
                                                  const int* __restrict__ row_ptr,
                                                  const float* __restrict__ dinv,
                                                  const float* __restrict__ b2,
                                                  float* __restrict__ out, int n) {
    int node = (int)(((long long)blockIdx.x * 256 + threadIdx.x) >> 5);
    int lane = threadIdx.x & 63;
    int l32 = lane & 31;
    if (node >= n) return;
    int slot = l32 / 10;             // 0..2 active, 3 idle (l32 30,31)
    int j = l32 - slot * 10;
    bool act = slot < 3;
    float a0=0, a1=0, a2=0, a3=0;
    if (slot == 0) {
        uint2 u = t2[(size_t)node * 10 + j];
        a0 = bf_lo(u.x); a1 = bf_hi(u.x);
        a2 = bf_lo(u.y); a3 = bf_hi(u.y);
    }
    int e0 = row_ptr[node];
    int cnt = act ? (row_ptr[node + 1] - e0) : 0;
    int p = slot;
    for (; p + 3 < cnt; p += 6) {
        int s0 = srcs[e0 + p], s1 = srcs[e0 + p + 3];
        uint2 u0 = t2[(size_t)s0 * 10 + j];
        uint2 u1 = t2[(size_t)s1 * 10 + j];
        a0 += bf_lo(u0.x) + bf_lo(u1.x);  a1 += bf_hi(u0.x) + bf_hi(u1.x);
        a2 += bf_lo(u0.y) + bf_lo(u1.y);  a3 += bf_hi(u0.y) + bf_hi(u1.y);
    }
    for (; p < cnt; p += 3) {
        int s0 = srcs[e0 + p];
        uint2 u0 = t2[(size_t)s0 * 10 + j];
        a0 += bf_lo(u0.x);  a1 += bf_hi(u0.x);
        a2 += bf_lo(u0.y);  a3 += bf_hi(u0.y);
    }
    // combine the 3 slots into l32 0..9 (reads stay within the same half)
    float t0 = a0 + __shfl(a0, lane + 10) + __shfl(a0, lane + 20);
    float t1 = a1 + __shfl(a1, lane + 10) + __shfl(a1, lane + 20);
    float t2s = a2 + __shfl(a2, lane + 10) + __shfl(a2, lane + 20);
    float t3 = a3 + __shfl(a3, lane + 10) + __shfl(a3, lane + 20);
    bool actc = l32 < 10;
    float di = dinv[node];
    float4 bb = actc ? *(const float4*)&b2[4 * l32] : make_float4(0, 0, 0, 0);
    float v0 = fmaf(t0, di, bb.x);
    float v1 = fmaf(t1, di, bb.y);
    float v2 = fmaf(t2s, di, bb.z);
    float v3 = fmaf(t3, di, bb.w);
    // softmax reduction within the 32-lane half (xor masks < 32)
    float mv = actc ? fmaxf(fmaxf(v0, v1), fmaxf(v2, v3)) : -INFINITY;
    for (int o = 16; o; o >>= 1) mv = fmaxf(mv, __shfl_xor(mv, o));
    float ex = actc ? (expf(v0 - mv) + expf(v1 - mv) + expf(v2 - mv) + expf(v3 - mv)) : 0.0f;
    float s = ex;
    for (int o = 16; o; o >>= 1) s += __shfl_xor(s, o);
    float ls = mv + logf(s);
    if (actc) {
        float4 r = make_float4(v0 - ls, v1 - ls, v2 - ls, v3 - ls);
        *(float4*)&out[(size_t)node * 40 + 4 * l32] = r;
    }
}

extern "C" void kernel_launch(void* const* d_in, const int* in_sizes, int n_in,
                              void* d_out, int out_size, void* d_ws, size_t ws_size,
                              hipStream_t stream) {
    const float* x  = (const float*)d_in[0];
    const int*   ei = (const int*)d_in[1];
    const float* W1 = (const float*)d_in[2];
    const float* b1 = (const float*)d_in[3];
    const float* W2 = (const float*)d_in[4];
    const float* b2 = (const float*)d_in[5];

    const int N = in_sizes[0] / F1;      // 100000
    const int E = in_sizes[1] / 2;       // 1600000
    const int* src = ei;
    const int* dst = ei + E;

    int bsh = 7;
    while ((((N - 1) >> bsh) + 1) > NB) ++bsh;
    const int NBu = ((N - 1) >> bsh) + 1;   // 782

    // workspace layout (16 B-aligned arrays first)
    uint4* h1b     = (uint4*)d_ws;                                // N*8 uint4 (bf16 hs)
    uint4* aggb    = h1b + (size_t)N * 8;                         // N*8 uint4 (relu agg bf16)
    uint2* tb      = (uint2*)(aggb + (size_t)N * 8);              // N*10 uint2 (bf16 ts)
    unsigned long long* pairs = (unsigned long long*)(tb + (size_t)N * 10);  // E
    int*   srcs    = (int*)(pairs + E);                           // E
    int*   row_ptr = srcs + E;                                    // N+1
    float* dinv    = (float*)(row_ptr + N + 1);                   // N
    int*   bcnt    = (int*)(dinv + N);                            // NB
    int*   bptr    = bcnt + NB;                                   // NB+1
    int*   gcur    = bptr + NB + 1;                               // NB
    float* outp    = (float*)d_out;                               // N*40

    const int B = 256;
    const int GT = (E + TILE - 1) / TILE;

    // --- CSR build (bucketed; emits row_ptr, dinv, srcs) ---
    hipMemsetAsync(bcnt, 0, NB * sizeof(int), stream);
    k_bhist<<<GT, B, 0, stream>>>(dst, bcnt, E, bsh);
    k_bscan<<<1, NB, 0, stream>>>(bcnt, bptr, gcur, row_ptr, N, E);
    k_bscatter<<<GT, B, 0, stream>>>(src, dst, gcur, pairs, E, bsh);
    k_final<<<NBu, B, 0, stream>>>(pairs, bptr, srcs, row_ptr, dinv, N, bsh);

    // --- layer 1: scaled GEMM (bf16) then plain-sum gather -> relu bf16 ---
    k_gemm1<<<(N + 3) / 4, B, 0, stream>>>(x, W1, dinv, (unsigned short*)h1b, N);
    k_gather<<<(N + 7) / 8, B, 0, stream>>>(h1b, srcs, row_ptr, dinv, b1, aggb, N);

    // --- layer 2: scaled transform (bf16), plain-sum gather + bias + log_softmax ---
    const int TB = 2048;
    k_trans2<<<TB, B, 0, stream>>>((const uint*)aggb, W2, dinv, (unsigned short*)tb, N, TB * 4);
    k_gather40<<<(N + 7) / 8, B, 0, stream>>>(tb, srcs, row_ptr, dinv, b2, outp, N);
}

// Round 12
// 291.305 us; speedup vs baseline: 1.9195x; 1.0160x over previous
//
#include <hip/hip_runtime.h>
#include <math.h>

#define F1 64   // input/hidden features
#define F2 40   // classes
#define NB 1024     // buckets for CSR build (bsh=7 -> 128 nodes/bucket)
#define TILE 4096   // edges per k_bscatter/k_bhist block
#define FCAP 3200   // max staged edges/bucket in k_final (25.6 KB); mean 2046, sigma 45

typedef unsigned int uint;

// ---------- bf16 helpers ----------
__device__ inline unsigned short f2bf(float f) {
    unsigned u = __float_as_uint(f);
    unsigned r = (u + 0x7FFFu + ((u >> 16) & 1u)) >> 16;   // RNE
    return (unsigned short)r;
}
__device__ inline uint packbf(float lo, float hi) {
    return (uint)f2bf(lo) | ((uint)f2bf(hi) << 16);
}
__device__ inline float bf_lo(uint u) { return __uint_as_float(u << 16); }
__device__ inline float bf_hi(uint u) { return __uint_as_float(u & 0xFFFF0000u); }

// ---------- pass 1a: bucket histogram ----------
__global__ __launch_bounds__(256) void k_bhist(const int* __restrict__ dst,
                                               int* __restrict__ bcnt, int e, int bsh) {
    __shared__ int h[NB];
    int tid = threadIdx.x;
    for (int i = tid; i < NB; i += 256) h[i] = 0;
    __syncthreads();
    int base = blockIdx.x * TILE;
    int lim = min(base + TILE, e);
    for (int i = base + tid; i < lim; i += 256) atomicAdd(&h[dst[i] >> bsh], 1);
    __syncthreads();
    for (int i = tid; i < NB; i += 256) if (h[i]) atomicAdd(&bcnt[i], h[i]);
}

// ---------- pass 1b: scan of bucket counts ----------
__global__ __launch_bounds__(NB) void k_bscan(const int* __restrict__ bcnt,
                                              int* __restrict__ bptr, int* __restrict__ gcur,
                                              int* __restrict__ row_ptr, int n, int e) {
    __shared__ int sh[NB];
    int t = threadIdx.x;
    sh[t] = bcnt[t];
    __syncthreads();
    for (int off = 1; off < NB; off <<= 1) {
        int v = (t >= off) ? sh[t - off] : 0;
        __syncthreads();
        sh[t] += v;
        __syncthreads();
    }
    int ex = t ? sh[t - 1] : 0;
    bptr[t] = ex;
    gcur[t] = ex;
    if (t == NB - 1) bptr[NB] = sh[NB - 1];
    if (t == 0) row_ptr[n] = e;
}

// ---------- pass 1c: bucket (src,dst) pairs ----------
__global__ __launch_bounds__(256) void k_bscatter(const int* __restrict__ src,
                                                  const int* __restrict__ dst,
                                                  int* gcur,
                                                  unsigned long long* __restrict__ pairs,
                                                  int e, int bsh) {
    __shared__ int lhist[NB];
    __shared__ int lstart[NB];
    __shared__ int delta[NB];
    __shared__ unsigned long long stage[TILE];
    int tid = threadIdx.x;
    for (int i = tid; i < NB; i += 256) lhist[i] = 0;
    __syncthreads();
    int base = blockIdx.x * TILE;
    int cnt = min(TILE, e - base);
    int sA[16], dA[16], rA[16];
#pragma unroll
    for (int k = 0; k < 16; ++k) {
        int i = base + k * 256 + tid;
        if (i < e) {
            sA[k] = src[i];
            dA[k] = dst[i];
            rA[k] = atomicAdd(&lhist[dA[k] >> bsh], 1);
        }
    }
    __syncthreads();
    if (tid < 64) {
        const int per = NB / 64;
        int v[per];
        int b0 = tid * per, s = 0;
#pragma unroll
        for (int j = 0; j < per; ++j) { v[j] = lhist[b0 + j]; s += v[j]; }
        int sc = s;
        for (int o = 1; o < 64; o <<= 1) { int u = __shfl_up(sc, o); if (tid >= o) sc += u; }
        int ex = sc - s;
#pragma unroll
        for (int j = 0; j < per; ++j) { lstart[b0 + j] = ex; ex += v[j]; }
    }
    __syncthreads();
    for (int i = tid; i < NB; i += 256) {
        int c = lhist[i];
        if (c) delta[i] = atomicAdd(&gcur[i], c) - lstart[i];
    }
    __syncthreads();
#pragma unroll
    for (int k = 0; k < 16; ++k) {
        int i = base + k * 256 + tid;
        if (i < e) {
            int b = dA[k] >> bsh;
            stage[lstart[b] + rA[k]] =
                ((unsigned long long)(unsigned)sA[k] << 32) | (unsigned)dA[k];
        }
    }
    __syncthreads();
    for (int p = tid; p < cnt; p += 256) {
        unsigned long long pr = stage[p];
        int b = ((int)(unsigned)pr) >> bsh;
        pairs[delta[b] + p] = pr;
    }
}

// ---------- pass 2: per-bucket finalize: row_ptr, dinv, srcs ----------
__global__ __launch_bounds__(256) void k_final(const unsigned long long* __restrict__ pairs,
                                               const int* __restrict__ bptr,
                                               int* __restrict__ srcs,
                                               int* __restrict__ row_ptr,
                                               float* __restrict__ dinv,
                                               int n, int bsh) {
    __shared__ int ldeg[128];
    __shared__ int lrow[128];
    __shared__ int lcur[128];
    __shared__ unsigned long long stg[FCAP];
    int b = blockIdx.x, tid = threadIdx.x;
    int beg = bptr[b], cnt = bptr[b + 1] - beg;
    int node0 = b << bsh;
    int bnodes = 1 << bsh;   // 128
    for (int i = tid; i < bnodes; i += 256) { ldeg[i] = 0; lcur[i] = 0; }
    bool fit = cnt <= FCAP;
    __syncthreads();
    if (fit) {
        for (int p = tid; p < cnt; p += 256) {
            unsigned long long pr = pairs[beg + p];
            stg[p] = pr;
            atomicAdd(&ldeg[((int)(unsigned)pr) - node0], 1);
        }
    } else {
        for (int p = tid; p < cnt; p += 256)
            atomicAdd(&ldeg[((int)(unsigned)pairs[beg + p]) - node0], 1);
    }
    __syncthreads();
    if (tid < 64) {
        int per = bnodes >> 6;   // 2
        int b0 = tid * per, s = 0;
        for (int j = 0; j < per; ++j) s += ldeg[b0 + j];
        int sc = s;
        for (int o = 1; o < 64; o <<= 1) { int u = __shfl_up(sc, o); if (tid >= o) sc += u; }
        int ex = sc - s;
        for (int j = 0; j < per; ++j) { lrow[b0 + j] = ex; ex += ldeg[b0 + j]; }
    }
    __syncthreads();
    for (int i = tid; i < bnodes; i += 256) {
        int node = node0 + i;
        if (node < n) {
            row_ptr[node] = beg + lrow[i];
            dinv[node] = rsqrtf((float)(ldeg[i] + 1));   // +1 self loop
        }
    }
    if (fit) {
        for (int p = tid; p < cnt; p += 256) {
            unsigned long long pr = stg[p];
            int dl = ((int)(unsigned)pr) - node0;
            int r = atomicAdd(&lcur[dl], 1);
            srcs[beg + lrow[dl] + r] = (int)(pr >> 32);
        }
    } else {
        for (int p = tid; p < cnt; p += 256) {
            unsigned long long pr = pairs[beg + p];
            int dl = ((int)(unsigned)pr) - node0;
            int r = atomicAdd(&lcur[dl], 1);
            srcs[beg + lrow[dl] + r] = (int)(pr >> 32);
        }
    }
}

// ---------- GEMM1 (trans2-style): hs = dinv[row] * (x @ W1), bf16 ----------
// lane = output column; W1 column in 64 VGPRs; x row via wave-uniform s_loads.
__global__ __launch_bounds__(256) void k_gemm1(const float* __restrict__ x,
                                               const float* __restrict__ W,
                                               const float* __restrict__ dinv,
                                               unsigned short* __restrict__ h, int n,
                                               int nwaves) {
    int wid = blockIdx.x * 4 + (threadIdx.x >> 6);
    int lane = threadIdx.x & 63;
    float wcol[64];
#pragma unroll
    for (int k = 0; k < 64; ++k)
        wcol[k] = W[k * 64 + lane];
    for (int node = wid; node < n; node += nwaves) {
        int node_u = __builtin_amdgcn_readfirstlane(node);
        const float* arow = x + (size_t)node_u * 64;
        float acc = 0.0f;
#pragma unroll
        for (int k4 = 0; k4 < 16; ++k4) {
            float4 a = *(const float4*)(arow + k4 * 4);   // wave-uniform -> s_load
            acc = fmaf(a.x, wcol[k4 * 4 + 0], acc);
            acc = fmaf(a.y, wcol[k4 * 4 + 1], acc);
            acc = fmaf(a.z, wcol[k4 * 4 + 2], acc);
            acc = fmaf(a.w, wcol[k4 * 4 + 3], acc);
        }
        h[(size_t)node_u * 64 + lane] = f2bf(acc * dinv[node_u]);
    }
}

// ---------- layer-1 gather: one node per HALF-wave, 4 slots x 8 lanes x uint4 ----------
__global__ __launch_bounds__(256) void k_gather(const uint4* __restrict__ h4,
                                                const int* __restrict__ srcs,
                                                const int* __restrict__ row_ptr,
                                                const float* __restrict__ dinv,
                                                const float* __restrict__ b,
                                                uint4* __restrict__ aggb, int n) {
    int node = (int)(((long long)blockIdx.x * 256 + threadIdx.x) >> 5);
    int l32 = threadIdx.x & 31;
    if (node >= n) return;
    int slot = l32 >> 3, j = l32 & 7;
    float a0x=0,a0y=0,a1x=0,a1y=0,a2x=0,a2y=0,a3x=0,a3y=0;
    if (slot == 0) {
        uint4 u = h4[(size_t)node * 8 + j];
        a0x = bf_lo(u.x); a0y = bf_hi(u.x);
        a1x = bf_lo(u.y); a1y = bf_hi(u.y);
        a2x = bf_lo(u.z); a2y = bf_hi(u.z);
        a3x = bf_lo(u.w); a3y = bf_hi(u.w);
    }
    int e0 = row_ptr[node], cnt = row_ptr[node + 1] - e0;
    int p = slot;
    for (; p + 4 < cnt; p += 8) {
        int s0 = srcs[e0 + p], s1 = srcs[e0 + p + 4];
        uint4 u0 = h4[(size_t)s0 * 8 + j];
        uint4 u1 = h4[(size_t)s1 * 8 + j];
        a0x += bf_lo(u0.x) + bf_lo(u1.x);  a0y += bf_hi(u0.x) + bf_hi(u1.x);
        a1x += bf_lo(u0.y) + bf_lo(u1.y);  a1y += bf_hi(u0.y) + bf_hi(u1.y);
        a2x += bf_lo(u0.z) + bf_lo(u1.z);  a2y += bf_hi(u0.z) + bf_hi(u1.z);
        a3x += bf_lo(u0.w) + bf_lo(u1.w);  a3y += bf_hi(u0.w) + bf_hi(u1.w);
    }
    for (; p < cnt; p += 4) {
        int s0 = srcs[e0 + p];
        uint4 u0 = h4[(size_t)s0 * 8 + j];
        a0x += bf_lo(u0.x);  a0y += bf_hi(u0.x);
        a1x += bf_lo(u0.y);  a1y += bf_hi(u0.y);
        a2x += bf_lo(u0.z);  a2y += bf_hi(u0.z);
        a3x += bf_lo(u0.w);  a3y += bf_hi(u0.w);
    }
#define COMB(o) \
    a0x += __shfl_xor(a0x, o); a0y += __shfl_xor(a0y, o); \
    a1x += __shfl_xor(a1x, o); a1y += __shfl_xor(a1y, o); \
    a2x += __shfl_xor(a2x, o); a2y += __shfl_xor(a2y, o); \
    a3x += __shfl_xor(a3x, o); a3y += __shfl_xor(a3y, o);
    COMB(8) COMB(16)
#undef COMB
    if (slot == 0) {
        float di = dinv[node];
        float4 bl = *(const float4*)&b[8 * j];
        float4 bh = *(const float4*)&b[8 * j + 4];
        float v0 = fmaxf(fmaf(a0x, di, bl.x), 0.0f);
        float v1 = fmaxf(fmaf(a0y, di, bl.y), 0.0f);
        float v2 = fmaxf(fmaf(a1x, di, bl.z), 0.0f);
        float v3 = fmaxf(fmaf(a1y, di, bl.w), 0.0f);
        float v4 = fmaxf(fmaf(a2x, di, bh.x), 0.0f);
        float v5 = fmaxf(fmaf(a2y, di, bh.y), 0.0f);
        float v6 = fmaxf(fmaf(a3x, di, bh.z), 0.0f);
        float v7 = fmaxf(fmaf(a3y, di, bh.w), 0.0f);
        uint4 r;
        r.x = packbf(v0, v1); r.y = packbf(v2, v3);
        r.z = packbf(v4, v5); r.w = packbf(v6, v7);
        aggb[(size_t)node * 8 + j] = r;
    }
}

// ---------- layer-2 transform: ts = dinv * (agg_relu_bf16 @ W2), bf16 ----------
__global__ __launch_bounds__(256) void k_trans2(const uint* __restrict__ aggu,
                                                const float* __restrict__ W2,
                                                const float* __restrict__ dinv,
                                                unsigned short* __restrict__ t, int n,
                                                int nwaves) {
    int wid = blockIdx.x * 4 + (threadIdx.x >> 6);
    int lane = threadIdx.x & 63;
    float wcol[64];
#pragma unroll
    for (int k = 0; k < 64; ++k)
        wcol[k] = (lane < 40) ? W2[k * 40 + lane] : 0.0f;
    for (int node = wid; node < n; node += nwaves) {
        int node_u = __builtin_amdgcn_readfirstlane(node);
        const uint* arow = aggu + (size_t)node_u * 32;
        float acc = 0.0f;
#pragma unroll
        for (int k4 = 0; k4 < 8; ++k4) {
            uint4 a = *(const uint4*)(arow + k4 * 4);   // wave-uniform -> s_load
            acc = fmaf(bf_lo(a.x), wcol[8 * k4 + 0], acc);
            acc = fmaf(bf_hi(a.x), wcol[8 * k4 + 1], acc);
            acc = fmaf(bf_lo(a.y), wcol[8 * k4 + 2], acc);
            acc = fmaf(bf_hi(a.y), wcol[8 * k4 + 3], acc);
            acc = fmaf(bf_lo(a.z), wcol[8 * k4 + 4], acc);
            acc = fmaf(bf_hi(a.z), wcol[8 * k4 + 5], acc);
            acc = fmaf(bf_lo(a.w), wcol[8 * k4 + 6], acc);
            acc = fmaf(bf_hi(a.w), wcol[8 * k4 + 7], acc);
        }
        float di = dinv[node_u];
        if (lane < 40) t[(size_t)node_u * 40 + lane] = f2bf(acc * di);
    }
}

// ---------- layer-2 gather: one node per HALF-wave, 3 slots x 10 lanes x uint2 ----------
__global__ __launch_bounds__(256) void k_gather40(const uint2* __restrict__ t2,
                                                  const int* __restrict__ srcs,
                                                  const int* __restrict__ row_ptr,
                                                  const float* __restrict__ dinv,
                                                  const float* __restrict__ b2,
                                                  float* __restrict__ out, int n) {
    int node = (int)(((long long)blockIdx.x * 256 + threadIdx.x) >> 5);
    int lane = threadIdx.x & 63;
    int l32 = lane & 31;
    if (node >= n) return;
    int slot = l32 / 10;             // 0..2 active, 3 idle (l32 30,31)
    int j = l32 - slot * 10;
    bool act = slot < 3;
    float a0=0, a1=0, a2=0, a3=0;
    if (slot == 0) {
        uint2 u = t2[(size_t)node * 10 + j];
        a0 = bf_lo(u.x); a1 = bf_hi(u.x);
        a2 = bf_lo(u.y); a3 = bf_hi(u.y);
    }
    int e0 = row_ptr[node];
    int cnt = act ? (row_ptr[node + 1] - e0) : 0;
    int p = slot;
    for (; p + 3 < cnt; p += 6) {
        int s0 = srcs[e0 + p], s1 = srcs[e0 + p + 3];
        uint2 u0 = t2[(size_t)s0 * 10 + j];
        uint2 u1 = t2[(size_t)s1 * 10 + j];
        a0 += bf_lo(u0.x) + bf_lo(u1.x);  a1 += bf_hi(u0.x) + bf_hi(u1.x);
        a2 += bf_lo(u0.y) + bf_lo(u1.y);  a3 += bf_hi(u0.y) + bf_hi(u1.y);
    }
    for (; p < cnt; p += 3) {
        int s0 = srcs[e0 + p];
        uint2 u0 = t2[(size_t)s0 * 10 + j];
        a0 += bf_lo(u0.x);  a1 += bf_hi(u0.x);
        a2 += bf_lo(u0.y);  a3 += bf_hi(u0.y);
    }
    float t0 = a0 + __shfl(a0, lane + 10) + __shfl(a0, lane + 20);
    float t1 = a1 + __shfl(a1, lane + 10) + __shfl(a1, lane + 20);
    float t2s = a2 + __shfl(a2, lane + 10) + __shfl(a2, lane + 20);
    float t3 = a3 + __shfl(a3, lane + 10) + __shfl(a3, lane + 20);
    bool actc = l32 < 10;
    float di = dinv[node];
    float4 bb = actc ? *(const float4*)&b2[4 * l32] : make_float4(0, 0, 0, 0);
    float v0 = fmaf(t0, di, bb.x);
    float v1 = fmaf(t1, di, bb.y);
    float v2 = fmaf(t2s, di, bb.z);
    float v3 = fmaf(t3, di, bb.w);
    float mv = actc ? fmaxf(fmaxf(v0, v1), fmaxf(v2, v3)) : -INFINITY;
    for (int o = 16; o; o >>= 1) mv = fmaxf(mv, __shfl_xor(mv, o));
    float ex = actc ? (expf(v0 - mv) + expf(v1 - mv) + expf(v2 - mv) + expf(v3 - mv)) : 0.0f;
    float s = ex;
    for (int o = 16; o; o >>= 1) s += __shfl_xor(s, o);
    float ls = mv + logf(s);
    if (actc) {
        float4 r = make_float4(v0 - ls, v1 - ls, v2 - ls, v3 - ls);
        *(float4*)&out[(size_t)node * 40 + 4 * l32] = r;
    }
}

extern "C" void kernel_launch(void* const* d_in, const int* in_sizes, int n_in,
                              void* d_out, int out_size, void* d_ws, size_t ws_size,
                              hipStream_t stream) {
    const float* x  = (const float*)d_in[0];
    const int*   ei = (const int*)d_in[1];
    const float* W1 = (const float*)d_in[2];
    const float* b1 = (const float*)d_in[3];
    const float* W2 = (const float*)d_in[4];
    const float* b2 = (const float*)d_in[5];

    const int N = in_sizes[0] / F1;      // 100000
    const int E = in_sizes[1] / 2;       // 1600000
    const int* src = ei;
    const int* dst = ei + E;

    int bsh = 7;
    while ((((N - 1) >> bsh) + 1) > NB) ++bsh;
    const int NBu = ((N - 1) >> bsh) + 1;   // 782

    // workspace layout (16 B-aligned arrays first)
    uint4* h1b     = (uint4*)d_ws;                                // N*8 uint4 (bf16 hs)
    uint4* aggb    = h1b + (size_t)N * 8;                         // N*8 uint4 (relu agg bf16)
    uint2* tb      = (uint2*)(aggb + (size_t)N * 8);              // N*10 uint2 (bf16 ts)
    unsigned long long* pairs = (unsigned long long*)(tb + (size_t)N * 10);  // E
    int*   srcs    = (int*)(pairs + E);                           // E
    int*   row_ptr = srcs + E;                                    // N+1
    float* dinv    = (float*)(row_ptr + N + 1);                   // N
    int*   bcnt    = (int*)(dinv + N);                            // NB
    int*   bptr    = bcnt + NB;                                   // NB+1
    int*   gcur    = bptr + NB + 1;                               // NB
    float* outp    = (float*)d_out;                               // N*40

    const int B = 256;
    const int GT = (E + TILE - 1) / TILE;

    // --- CSR build (bucketed; emits row_ptr, dinv, srcs) ---
    hipMemsetAsync(bcnt, 0, NB * sizeof(int), stream);
    k_bhist<<<GT, B, 0, stream>>>(dst, bcnt, E, bsh);
    k_bscan<<<1, NB, 0, stream>>>(bcnt, bptr, gcur, row_ptr, N, E);
    k_bscatter<<<GT, B, 0, stream>>>(src, dst, gcur, pairs, E, bsh);
    k_final<<<NBu, B, 0, stream>>>(pairs, bptr, srcs, row_ptr, dinv, N, bsh);

    // --- layer 1: scaled GEMM (bf16, persistent waves) then plain-sum gather ---
    const int TB = 2048;
    k_gemm1<<<TB, B, 0, stream>>>(x, W1, dinv, (unsigned short*)h1b, N, TB * 4);
    k_gather<<<(N + 7) / 8, B, 0, stream>>>(h1b, srcs, row_ptr, dinv, b1, aggb, N);

    // --- layer 2: scaled transform (bf16), plain-sum gather + bias + log_softmax ---
    k_trans2<<<TB, B, 0, stream>>>((const uint*)aggb, W2, dinv, (unsigned short*)tb, N, TB * 4);
    k_gather40<<<(N + 7) / 8, B, 0, stream>>>(tb, srcs, row_ptr, dinv, b2, outp, N);
}